// Round 10
// baseline (2721.610 us; speedup 1.0000x reference)
//
#include <hip/hip_runtime.h>
#include <stdint.h>

#define IMGF 800.0f
#define CLIPF 4.135166556742356f

// ---------- helpers ----------
__device__ __forceinline__ uint32_t fkey(float x){
  uint32_t b = __float_as_uint(x);
  return (b & 0x80000000u) ? ~b : (b | 0x80000000u);
}

// descending bitonic sort of n (pow2) uint64 keys in LDS
__device__ void bitonic_desc(unsigned long long* k, int n, int tid, int nthr){
  for (int kk=2; kk<=n; kk<<=1){
    for (int j=kk>>1; j>0; j>>=1){
      __syncthreads();
      for (int i=tid; i<n; i+=nthr){
        int ixj = i ^ j;
        if (ixj > i){
          unsigned long long a = k[i], b = k[ixj];
          bool up = ((i & kk) == 0);
          if ((a < b) == up){ k[i]=b; k[ixj]=a; }
        }
      }
    }
  }
  __syncthreads();
}

// ---------- 0a. repack conv weights for implicit GEMM: wB[d*256+ic][oc] = w[oc][ic][d] ----------
__global__ __launch_bounds__(256) void repack_wB(
    const float* __restrict__ w, float* __restrict__ wB){
  int idx = blockIdx.x*256 + threadIdx.x;
  if (idx >= 2304*256) return;
  int oc = idx & 255; int rest = idx >> 8;
  int ic = rest & 255; int d = rest >> 8;
  wB[idx] = w[((size_t)oc*256 + ic)*9 + d];
}

// ---------- 0b. repack rpn head weights: wrp2[wv][cc][20], o = wv+4j ----------
__global__ __launch_bounds__(256) void repack_heads_w(
    const float* __restrict__ wc, const float* __restrict__ wb, float* __restrict__ wrp2){
  int idx = blockIdx.x*256 + threadIdx.x;
  if (idx >= 4*256*20) return;
  int j = idx % 20; int rest = idx/20;
  int cc = rest & 255; int wv = rest >> 8;
  int o = wv + 4*j;
  float v = 0.f;
  if (j < 19 && o < 75) v = (o<15) ? wc[o*256+cc] : wb[(o-15)*256+cc];
  wrp2[idx] = v;
}

// ---------- 1. RPN conv3x3 as implicit GEMM, 128(rows)x64(oc) tile ----------
// acc=32 regs (no spill, no cap). Grid 832 = 8 XCD-chunks x (26 row-tiles x 4 n-tiles):
// bid&7 = XCD, so each XCD's L2 keeps its 26 consecutive row-tiles' A-windows.
__global__ __launch_bounds__(256) void gemm_conv64(
    const float* __restrict__ featT, const float* __restrict__ wB,
    const float* __restrict__ bias, float* __restrict__ tP){
  __shared__ float As[16][132];
  __shared__ float Bs[16][68];
  const int tid = threadIdx.x;
  const int bid = blockIdx.x;
  const int xcd = bid & 7;
  const int jb  = bid >> 3;
  const int rt  = xcd*26 + (jb >> 2);
  const int bn  = (jb & 3) * 64;
  const int b = rt / 104;
  const int i = rt - b*104;
  int base, HW, W, posOff;
  if (i < 79)      { base = i*128;        HW = 10000; W = 100; posOff = 0; }
  else if (i < 99) { base = (i-79)*128;   HW = 2500;  W = 50;  posOff = 10000; }
  else             { base = (i-99)*128;   HW = 625;   W = 25;  posOff = 12500; }
  const int gRowBase = b*13125 + posOff;

  const int am  = tid >> 2;
  const int ak4 = (tid & 3) * 4;
  const int p0r = base + am, p1r = base + am + 64;
  const bool v0 = p0r < HW, v1 = p1r < HW;
  const int y0r = p0r / W, x0r = p0r - y0r*W;
  const int y1r = p1r / W, x1r = p1r - y1r*W;
  const float* row0 = featT + (size_t)(gRowBase + p0r)*256;
  const float* row1 = featT + (size_t)(gRowBase + p1r)*256;
  const int bk  = tid >> 4;          // 0..15
  const int bn4 = (tid & 15) * 4;

  const float4 zero4 = make_float4(0.f,0.f,0.f,0.f);
  float acc[2][4][4];
  #pragma unroll
  for (int qi=0;qi<2;qi++)
    #pragma unroll
    for (int ii=0;ii<4;ii++)
      #pragma unroll
      for (int jj=0;jj<4;jj++) acc[qi][ii][jj]=0.f;

  const int tn1 = (tid & 15)*4;
  const int tm1 = ((tid >> 4) & 15)*4;

  float4 pa0, pa1, pb0;
  int dcur = -1, shift = 0;
  bool ok0f = false, ok1f = false;

  auto stage_load = [&](int t){
    const int d_ = t >> 4;
    if (d_ != dcur){
      dcur = d_;
      const int q3 = (d_*11) >> 5;            // d/3
      const int dy = q3 - 1;
      const int dx = d_ - 3*q3 - 1;
      shift = (dy*W + dx)*256;
      ok0f = v0 && (unsigned)(y0r+dy) < (unsigned)W && (unsigned)(x0r+dx) < (unsigned)W;
      ok1f = v1 && (unsigned)(y1r+dy) < (unsigned)W && (unsigned)(x1r+dx) < (unsigned)W;
    }
    const int ic0 = (t & 15) << 4;
    pa0 = ok0f ? *reinterpret_cast<const float4*>(row0 + shift + ic0 + ak4) : zero4;
    pa1 = ok1f ? *reinterpret_cast<const float4*>(row1 + shift + ic0 + ak4) : zero4;
    const int kg = t*16;
    pb0 = *reinterpret_cast<const float4*>(&wB[(size_t)(kg+bk)*256 + bn + bn4]);
  };
  auto stage_store = [&](){
    As[ak4+0][am]=pa0.x; As[ak4+1][am]=pa0.y; As[ak4+2][am]=pa0.z; As[ak4+3][am]=pa0.w;
    As[ak4+0][am+64]=pa1.x; As[ak4+1][am+64]=pa1.y; As[ak4+2][am+64]=pa1.z; As[ak4+3][am+64]=pa1.w;
    *reinterpret_cast<float4*>(&Bs[bk][bn4]) = pb0;
  };

  stage_load(0);
  stage_store();
  __syncthreads();

  for (int t=0; t<144; ++t){
    if (t+1 < 144) stage_load(t+1);
    #pragma unroll
    for (int kk=0; kk<16; ++kk){
      float4 a0 = *reinterpret_cast<const float4*>(&As[kk][tm1]);
      float4 a1 = *reinterpret_cast<const float4*>(&As[kk][tm1+64]);
      float4 b0 = *reinterpret_cast<const float4*>(&Bs[kk][tn1]);
      float ar0[4]={a0.x,a0.y,a0.z,a0.w}, ar1[4]={a1.x,a1.y,a1.z,a1.w};
      float br[4]={b0.x,b0.y,b0.z,b0.w};
      #pragma unroll
      for (int ii=0;ii<4;ii++)
        #pragma unroll
        for (int jj=0;jj<4;jj++){
          acc[0][ii][jj] += ar0[ii]*br[jj];
          acc[1][ii][jj] += ar1[ii]*br[jj];
        }
    }
    if (t+1 < 144){
      __syncthreads();
      stage_store();
      __syncthreads();
    }
  }

  #pragma unroll
  for (int qi=0;qi<2;qi++){
    #pragma unroll
    for (int ii=0;ii<4;ii++){
      int p = base + tm1 + qi*64 + ii;
      if (p < HW){
        float* orow = tP + (size_t)(gRowBase + p)*256 + bn;
        float4 v;
        v.x = fmaxf(acc[qi][ii][0] + bias[bn+tn1+0], 0.f);
        v.y = fmaxf(acc[qi][ii][1] + bias[bn+tn1+1], 0.f);
        v.z = fmaxf(acc[qi][ii][2] + bias[bn+tn1+2], 0.f);
        v.w = fmaxf(acc[qi][ii][3] + bias[bn+tn1+3], 0.f);
        *reinterpret_cast<float4*>(&orow[tn1]) = v;
      }
    }
  }
}

// ---------- 2. RPN 1x1 heads, position-major input ----------
__global__ __launch_bounds__(256) void rpn_heads_pm(
    const float* __restrict__ tP, const float* __restrict__ wrp2,
    const float* __restrict__ bc, const float* __restrict__ bb,
    float* __restrict__ objs, float* __restrict__ dels,
    int HW, int posOff, int lvlOff){
  int b = blockIdx.y;
  int p0 = blockIdx.x*64;
  int lane = threadIdx.x & 63;
  int wv = __builtin_amdgcn_readfirstlane(threadIdx.x >> 6);
  __shared__ float sh[64][129];
  float acc[19];
  #pragma unroll
  for (int j=0;j<19;j++) acc[j]=0.f;
  const float* tb = tP + (size_t)(b*13125 + posOff)*256;
  for (int half=0; half<2; ++half){
    __syncthreads();
    for (int idx=threadIdx.x; idx<64*128; idx+=256){
      int px = idx>>7, c = idx&127;
      int p = p0+px;
      sh[px][c] = (p<HW) ? tb[(size_t)p*256 + half*128 + c] : 0.f;
    }
    __syncthreads();
    for (int c=0;c<128;c++){
      float v = sh[lane][c];
      int cc = half*128 + c;
      const float* wr = wrp2 + ((size_t)wv*256 + cc)*20;
      #pragma unroll
      for (int j=0;j<19;j++){
        int o = wv + 4*j;
        if (o < 75) acc[j] += v*wr[j];
      }
    }
  }
  int p = p0 + lane;
  if (p < HW){
    #pragma unroll
    for (int j=0;j<19;j++){
      int o = wv + 4*j;
      if (o < 75){
        if (o < 15){
          objs[(size_t)b*196875 + lvlOff + (size_t)p*15 + o] = acc[j] + bc[o];
        } else {
          int q = o-15;
          dels[((size_t)b*196875 + lvlOff + (size_t)p*15 + (q>>2))*4 + (q&3)] = acc[j] + bb[q];
        }
      }
    }
  }
}

// ---------- 3. feats NCHW -> position-major channel-last ----------
__global__ __launch_bounds__(256) void feat_transpose(
    const float* __restrict__ f, float* __restrict__ ft, int HW, int posOff){
  __shared__ float tile[32][33];
  int b = blockIdx.z;
  int p0 = blockIdx.x*32, c0 = blockIdx.y*32;
  int tx = threadIdx.x & 31, ty = threadIdx.x >> 5;
  #pragma unroll
  for (int i=0;i<4;i++){
    int c = c0 + ty + i*8;
    int p = p0 + tx;
    tile[ty+i*8][tx] = (p<HW) ? f[((size_t)b*256 + c)*HW + p] : 0.f;
  }
  __syncthreads();
  #pragma unroll
  for (int i=0;i<4;i++){
    int p = p0 + ty + i*8;
    int c = c0 + tx;
    if (p < HW) ft[((size_t)b*13125 + posOff + p)*256 + c] = tile[tx][ty+i*8];
  }
}

// ---------- 4. per (batch,level) exact top-500 + decode ----------
__global__ __launch_bounds__(1024) void rpn_topk_decode(
    const float* __restrict__ objs, const float* __restrict__ dels,
    float* __restrict__ lvl_boxes, float* __restrict__ lvl_scores){
  const int lvl = blockIdx.x, b = blockIdx.y;
  const int Ns[3]   = {150000,37500,9375};
  const int Offs[3] = {0,150000,187500};
  const int Wl[3]   = {100,50,25};
  const float strid[3] = {8.f,16.f,32.f};
  const int N = Ns[lvl];
  const float* sc = objs + (size_t)b*196875 + Offs[lvl];
  __shared__ uint32_t hist[2048];
  __shared__ uint32_t sPrefix;
  __shared__ int sKrem;
  __shared__ int sCnt;
  __shared__ unsigned long long keys[2048];
  int tid = threadIdx.x;
  if (tid==0){ sKrem=500; sPrefix=0; }
  for (int i=tid;i<2048;i+=1024) hist[i]=0u;
  __syncthreads();
  for (int i=tid;i<N;i+=1024){ uint32_t u=fkey(sc[i]); atomicAdd(&hist[u>>21],1u); }
  __syncthreads();
  if (tid==0){
    int cum=0, K=sKrem;
    for (int i=2047;i>=0;i--){ int c=(int)hist[i]; if (cum+c>=K){ sPrefix=(uint32_t)i<<21; sKrem=K-cum; break;} cum+=c; }
  }
  __syncthreads();
  uint32_t pref1 = sPrefix;
  for (int i=tid;i<2048;i+=1024) hist[i]=0u;
  __syncthreads();
  for (int i=tid;i<N;i+=1024){ uint32_t u=fkey(sc[i]); if ((u & 0xFFE00000u)==pref1) atomicAdd(&hist[(u>>10)&0x7FFu],1u); }
  __syncthreads();
  if (tid==0){
    int cum=0, K=sKrem;
    for (int i=2047;i>=0;i--){ int c=(int)hist[i]; if (cum+c>=K){ sPrefix=pref1|((uint32_t)i<<10); sKrem=K-cum; break;} cum+=c; }
  }
  __syncthreads();
  uint32_t pref2 = sPrefix;
  for (int i=tid;i<2048;i+=1024) hist[i]=0u;
  __syncthreads();
  for (int i=tid;i<N;i+=1024){ uint32_t u=fkey(sc[i]); if ((u & 0xFFFFFC00u)==pref2) atomicAdd(&hist[u & 0x3FFu],1u); }
  __syncthreads();
  if (tid==0){
    int cum=0, K=sKrem;
    for (int i=1023;i>=0;i--){ int c=(int)hist[i]; if (cum+c>=K){ sPrefix=pref2|(uint32_t)i; break;} cum+=c; }
    sCnt=0;
  }
  __syncthreads();
  uint32_t T = sPrefix;
  for (int i=tid;i<N;i+=1024){
    uint32_t u=fkey(sc[i]);
    if (u>=T){ int k=atomicAdd(&sCnt,1); if (k<2048) keys[k]=((unsigned long long)u<<32)|(uint32_t)(~(uint32_t)i); }
  }
  __syncthreads();
  int m = sCnt; if (m>2048) m=2048;
  int n = 512; while (n<m) n<<=1;
  for (int i=tid;i<n;i+=1024) if (i>=m) keys[i]=0ull;
  __syncthreads();
  bitonic_desc(keys, n, tid, 1024);
  if (tid < 500){
    unsigned long long key = keys[tid];
    uint32_t idx = ~(uint32_t)(key & 0xFFFFFFFFull);
    float score = sc[idx];
    int p = idx/15, a = idx - p*15;
    int W = Wl[lvl];
    int hh = p / W, ww = p - hh*W;
    int r5 = a/5, s5 = a - r5*5;
    const float ratios[3] = {0.5f,1.0f,2.0f};
    const float scales[5] = {32.f,64.f,128.f,256.f,512.f};
    float hr = sqrtf(ratios[r5]); float wr = 1.0f/hr;
    float wsz = wr*scales[s5], hsz = hr*scales[s5];
    float sx = (float)ww*strid[lvl], sy = (float)hh*strid[lvl];
    float ax1 = sx - 0.5f*wsz, ay1 = sy - 0.5f*hsz;
    float ax2 = sx + 0.5f*wsz, ay2 = sy + 0.5f*hsz;
    const float* dl = dels + ((size_t)b*196875 + Offs[lvl] + idx)*4;
    float bw = ax2-ax1, bh = ay2-ay1;
    float cx = ax1 + 0.5f*bw, cy = ay1 + 0.5f*bh;
    float dx = dl[0], dy = dl[1];
    float dw = fminf(dl[2], CLIPF), dh = fminf(dl[3], CLIPF);
    float pcx = dx*bw + cx, pcy = dy*bh + cy;
    float pw = expf(dw)*bw, ph = expf(dh)*bh;
    float x1 = fminf(fmaxf(pcx - 0.5f*pw, 0.f), IMGF);
    float y1 = fminf(fmaxf(pcy - 0.5f*ph, 0.f), IMGF);
    float x2 = fminf(fmaxf(pcx + 0.5f*pw, 0.f), IMGF);
    float y2 = fminf(fmaxf(pcy + 0.5f*ph, 0.f), IMGF);
    int oidx = b*1500 + lvl*500 + tid;
    lvl_boxes[oidx*4+0]=x1; lvl_boxes[oidx*4+1]=y1;
    lvl_boxes[oidx*4+2]=x2; lvl_boxes[oidx*4+3]=y2;
    bool valid = (x2-x1 >= 1e-3f) && (y2-y1 >= 1e-3f);
    lvl_scores[oidx] = valid ? score : -1e9f;
  }
}

// ---------- 5a. NMS: sort by score, emit sorted offset-boxes + order ----------
__global__ __launch_bounds__(1024) void nms_sort(
    const float* __restrict__ lvl_boxes, const float* __restrict__ lvl_scores,
    float* __restrict__ snb, int* __restrict__ sorder){
  int b = blockIdx.x, tid = threadIdx.x;
  __shared__ unsigned long long keys[2048];
  const float* ls = lvl_scores + (size_t)b*1500;
  const float* lb = lvl_boxes + (size_t)b*1500*4;
  for (int i=tid;i<2048;i+=1024)
    keys[i] = (i<1500) ? (((unsigned long long)fkey(ls[i])<<32)|(uint32_t)(~(uint32_t)i)) : 0ull;
  __syncthreads();
  bitonic_desc(keys, 2048, tid, 1024);
  for (int r=tid;r<1536;r+=1024){
    if (r < 1500){
      int idx = (int)(~(uint32_t)keys[r]);
      sorder[(size_t)b*1536 + r] = idx;
      float offv = (float)(idx/500) * (IMGF + 16.0f);
      float* pp = snb + ((size_t)b*1536 + r)*4;
      pp[0]=lb[idx*4+0]+offv; pp[1]=lb[idx*4+1]+offv;
      pp[2]=lb[idx*4+2]+offv; pp[3]=lb[idx*4+3]+offv;
    } else {
      sorder[(size_t)b*1536 + r] = 0;
      float* pp = snb + ((size_t)b*1536 + r)*4;
      pp[0]=pp[1]=pp[2]=pp[3]=0.f;
    }
  }
}

// ---------- 5b. NMS: IoU suppression bitmask matrix ----------
__global__ __launch_bounds__(256) void nms_mask(
    const float* __restrict__ snb, unsigned long long* __restrict__ masks){
  int b = blockIdx.y;
  int i0 = blockIdx.x*64;
  __shared__ float sbx[1536][4];
  for (int t=threadIdx.x; t<1536*4; t+=256)
    sbx[t>>2][t&3] = snb[(size_t)b*1536*4 + t];
  __syncthreads();
  int il = threadIdx.x >> 2;
  int wq = threadIdx.x & 3;
  int i = i0 + il;
  float ax1=sbx[i][0], ay1=sbx[i][1], ax2=sbx[i][2], ay2=sbx[i][3];
  float aa=(ax2-ax1)*(ay2-ay1);
  #pragma unroll
  for (int wofs=0; wofs<6; ++wofs){
    int w = wq*6 + wofs;
    unsigned long long m = 0ull;
    if (i < 1500){
      for (int jj=0; jj<64; ++jj){
        int j = w*64 + jj;
        if (j > i && j < 1500){
          float bx1=sbx[j][0],by1=sbx[j][1],bx2=sbx[j][2],by2=sbx[j][3];
          float ab=(bx2-bx1)*(by2-by1);
          float lx=fmaxf(ax1,bx1), ly=fmaxf(ay1,by1);
          float rx=fminf(ax2,bx2), ry=fminf(ay2,by2);
          float iw=fmaxf(rx-lx,0.f), ih=fmaxf(ry-ly,0.f);
          float inter=iw*ih;
          if (inter/(aa+ab-inter+1e-9f) > 0.7f) m |= (1ull<<jj);
        }
      }
    }
    masks[((size_t)b*1536 + i)*24 + w] = m;
  }
}

// ---------- 5c. NMS: serial bitmask scan + final top-512 gather ----------
__global__ __launch_bounds__(1024) void nms_scan_final(
    const unsigned long long* __restrict__ masks, const int* __restrict__ sorder,
    const float* __restrict__ lvl_boxes, const float* __restrict__ lvl_scores,
    float* __restrict__ props){
  int b = blockIdx.x, tid = threadIdx.x;
  __shared__ unsigned long long cm[128][24];
  __shared__ volatile unsigned long long keepw[24];
  __shared__ unsigned char korig[1536];
  __shared__ unsigned long long keys[2048];
  if (tid < 24) keepw[tid] = (tid==23) ? ((1ull<<28)-1ull) : ~0ull;
  for (int c=0; c<12; ++c){
    __syncthreads();
    for (int t=tid; t<128*24; t+=1024)
      cm[t/24][t%24] = masks[((size_t)b*1536 + c*128)*24 + t];
    __syncthreads();
    if (tid < 24){
      int lim = (c==11) ? 84 : 128;
      for (int il=0; il<lim; ++il){
        int i = c*128 + il;
        unsigned long long kw = keepw[i>>6];
        if ((kw>>(i&63)) & 1ull) keepw[tid] &= ~cm[il][tid];
      }
    }
  }
  __syncthreads();
  for (int r=tid; r<1500; r+=1024){
    unsigned long long kw = keepw[r>>6];
    korig[sorder[(size_t)b*1536 + r]] = (unsigned char)((kw>>(r&63)) & 1ull);
  }
  __syncthreads();
  const float* ls = lvl_scores + (size_t)b*1500;
  const float* lb = lvl_boxes + (size_t)b*1500*4;
  for (int i=tid;i<2048;i+=1024){
    if (i<1500){
      float s = korig[i] ? ls[i] : -1e9f;
      keys[i] = ((unsigned long long)fkey(s)<<32)|(uint32_t)(~(uint32_t)i);
    } else keys[i]=0ull;
  }
  __syncthreads();
  bitonic_desc(keys, 2048, tid, 1024);
  for (int j=tid;j<512;j+=1024){
    int idx = (int)(~(uint32_t)keys[j]);
    float* pp = props + ((size_t)b*512 + j)*4;
    pp[0]=lb[idx*4+0]; pp[1]=lb[idx*4+1]; pp[2]=lb[idx*4+2]; pp[3]=lb[idx*4+3];
  }
}

// ---------- 6. ROI align ----------
__global__ __launch_bounds__(256) void roi_align(
    const float* __restrict__ featT, const float* __restrict__ props,
    float* __restrict__ roiX){
  int blk = blockIdx.x;
  int b = blk >> 9, n = blk & 511;
  const float* box = props + ((size_t)b*512 + n)*4;
  float x1=box[0], y1=box[1], x2=box[2], y2=box[3];
  float area = fmaxf(x2-x1,0.f)*fmaxf(y2-y1,0.f);
  float kf = floorf(4.0f + log2f(sqrtf(area)/224.0f + 1e-6f));
  kf = fminf(fmaxf(kf, 3.f), 5.f);
  int lvl = (int)kf - 3;
  const int Wl[3] = {100,50,25};
  const int posOff[3] = {0,10000,12500};
  const float strid[3] = {8.f,16.f,32.f};
  float scl = 1.0f/strid[lvl];
  float hw = (float)Wl[lvl];
  float rx1 = x1*scl, ry1 = y1*scl;
  float rw = fmaxf(x2*scl - rx1, 1.0f), rh = fmaxf(y2*scl - ry1, 1.0f);
  float bw = rw/7.0f, bh = rh/7.0f;
  __shared__ int sIdx[196][4];
  __shared__ float sW[196][4];
  int t = threadIdx.x;
  if (t < 196){
    int bin = t>>2, s = t&3;
    int py = bin/7, px = bin - py*7;
    int sy = s>>1, sx = s&1;
    float sgy = ((float)sy + 0.5f)*0.5f, sgx = ((float)sx + 0.5f)*0.5f;
    float Y = ry1 + ((float)py + sgy)*bh;
    float X = rx1 + ((float)px + sgx)*bw;
    Y = fminf(fmaxf(Y,0.f), hw-1.0f);
    X = fminf(fmaxf(X,0.f), hw-1.0f);
    float y0 = floorf(Y), x0 = floorf(X);
    float ly = Y-y0, lx = X-x0;
    int y0i=(int)y0, x0i=(int)x0;
    int hi = Wl[lvl]-1;
    int y1i = (y0i+1<hi)?(y0i+1):hi;
    int x1i = (x0i+1<hi)?(x0i+1):hi;
    int W = Wl[lvl];
    int base = b*13125 + posOff[lvl];
    sIdx[t][0] = (base + y0i*W + x0i)*256;
    sIdx[t][1] = (base + y0i*W + x1i)*256;
    sIdx[t][2] = (base + y1i*W + x0i)*256;
    sIdx[t][3] = (base + y1i*W + x1i)*256;
    sW[t][0]=(1.f-ly)*(1.f-lx); sW[t][1]=(1.f-ly)*lx;
    sW[t][2]=ly*(1.f-lx);       sW[t][3]=ly*lx;
  }
  __syncthreads();
  int c = t;
  float* orow = roiX + ((size_t)b*512 + n)*12544 + (size_t)c*49;
  for (int bin=0;bin<49;bin++){
    float acc = 0.f;
    #pragma unroll
    for (int s=0;s<4;s++){
      int tt = bin*4+s;
      acc += sW[tt][0]*featT[sIdx[tt][0]+c] + sW[tt][1]*featT[sIdx[tt][1]+c]
           + sW[tt][2]*featT[sIdx[tt][2]+c] + sW[tt][3]*featT[sIdx[tt][3]+c];
    }
    orow[bin] = acc*0.25f;
  }
}

// ---------- 7. split-K GEMM, 128(M)x64(N) tile, k-tile 32 ----------
__global__ __launch_bounds__(256) void gemm64(
    const float* __restrict__ Am, const float* __restrict__ Bm,
    float* __restrict__ part, int M, int N, int K, int KC){
  __shared__ float As[32][132];
  __shared__ float Bs[32][68];
  const int tid = threadIdx.x;
  const int bn = blockIdx.x*64, bm = blockIdx.y*128, kz = blockIdx.z;
  const int k0 = kz*KC;
  const int nsteps = KC/32;
  const int tn1 = (tid & 15)*4;
  const int tm1 = ((tid >> 4) & 15)*4;
  float acc[2][4][4];
  #pragma unroll
  for (int qi=0;qi<2;qi++)
    #pragma unroll
    for (int i=0;i<4;i++)
      #pragma unroll
      for (int j=0;j<4;j++) acc[qi][i][j]=0.f;

  const int am  = tid >> 2;          // A rows am, am+64
  const int ak8 = (tid & 3)*8;       // A k offsets ak8..ak8+7 (2 float4)
  const int bk  = tid >> 4;          // B k rows bk, bk+16
  const int bn4 = (tid & 15)*4;      // B col offset
  float4 pa00, pa01, pa10, pa11, pb0, pb1;

  auto load = [&](int kb){
    pa00 = *reinterpret_cast<const float4*>(&Am[(size_t)(bm+am)*K + kb + ak8]);
    pa01 = *reinterpret_cast<const float4*>(&Am[(size_t)(bm+am)*K + kb + ak8 + 4]);
    pa10 = *reinterpret_cast<const float4*>(&Am[(size_t)(bm+am+64)*K + kb + ak8]);
    pa11 = *reinterpret_cast<const float4*>(&Am[(size_t)(bm+am+64)*K + kb + ak8 + 4]);
    pb0  = *reinterpret_cast<const float4*>(&Bm[(size_t)(kb+bk)*N + bn + bn4]);
    pb1  = *reinterpret_cast<const float4*>(&Bm[(size_t)(kb+bk+16)*N + bn + bn4]);
  };
  auto store = [&](){
    As[ak8+0][am]=pa00.x; As[ak8+1][am]=pa00.y; As[ak8+2][am]=pa00.z; As[ak8+3][am]=pa00.w;
    As[ak8+4][am]=pa01.x; As[ak8+5][am]=pa01.y; As[ak8+6][am]=pa01.z; As[ak8+7][am]=pa01.w;
    As[ak8+0][am+64]=pa10.x; As[ak8+1][am+64]=pa10.y; As[ak8+2][am+64]=pa10.z; As[ak8+3][am+64]=pa10.w;
    As[ak8+4][am+64]=pa11.x; As[ak8+5][am+64]=pa11.y; As[ak8+6][am+64]=pa11.z; As[ak8+7][am+64]=pa11.w;
    *reinterpret_cast<float4*>(&Bs[bk][bn4])    = pb0;
    *reinterpret_cast<float4*>(&Bs[bk+16][bn4]) = pb1;
  };

  load(k0);
  store();
  __syncthreads();

  for (int t=0; t<nsteps; ++t){
    if (t+1 < nsteps) load(k0 + (t+1)*32);
    #pragma unroll
    for (int kk=0; kk<32; ++kk){
      float4 a0 = *reinterpret_cast<const float4*>(&As[kk][tm1]);
      float4 a1 = *reinterpret_cast<const float4*>(&As[kk][tm1+64]);
      float4 b0 = *reinterpret_cast<const float4*>(&Bs[kk][tn1]);
      float ar0[4]={a0.x,a0.y,a0.z,a0.w}, ar1[4]={a1.x,a1.y,a1.z,a1.w};
      float br[4]={b0.x,b0.y,b0.z,b0.w};
      #pragma unroll
      for (int i=0;i<4;i++)
        #pragma unroll
        for (int j=0;j<4;j++){
          acc[0][i][j] += ar0[i]*br[j];
          acc[1][i][j] += ar1[i]*br[j];
        }
    }
    if (t+1 < nsteps){
      __syncthreads();
      store();
      __syncthreads();
    }
  }

  float* pz = part + (size_t)kz*M*N;
  #pragma unroll
  for (int qi=0;qi<2;qi++){
    #pragma unroll
    for (int i=0;i<4;i++){
      int row = bm + tm1 + qi*64 + i;
      float4 v = make_float4(acc[qi][i][0],acc[qi][i][1],acc[qi][i][2],acc[qi][i][3]);
      *reinterpret_cast<float4*>(&pz[(size_t)row*N + bn + tn1]) = v;
    }
  }
}

// reduce SPLITK=4 partials + bias (+relu). N must be pow2.
__global__ __launch_bounds__(256) void reduce_splitk(
    const float* __restrict__ part, const float* __restrict__ bias,
    float* __restrict__ out, int MN, int Nmask, int relu){
  int i4 = (blockIdx.x*256 + threadIdx.x)*4;
  if (i4 < MN){
    float4 s0 = *reinterpret_cast<const float4*>(&part[i4]);
    float4 s1 = *reinterpret_cast<const float4*>(&part[(size_t)MN + i4]);
    float4 s2 = *reinterpret_cast<const float4*>(&part[(size_t)2*MN + i4]);
    float4 s3 = *reinterpret_cast<const float4*>(&part[(size_t)3*MN + i4]);
    float4 bb = *reinterpret_cast<const float4*>(&bias[i4 & Nmask]);
    float4 r;
    r.x = s0.x+s1.x+s2.x+s3.x+bb.x;
    r.y = s0.y+s1.y+s2.y+s3.y+bb.y;
    r.z = s0.z+s1.z+s2.z+s3.z+bb.z;
    r.w = s0.w+s1.w+s2.w+s3.w+bb.w;
    if (relu){ r.x=fmaxf(r.x,0.f); r.y=fmaxf(r.y,0.f); r.z=fmaxf(r.z,0.f); r.w=fmaxf(r.w,0.f); }
    *reinterpret_cast<float4*>(&out[i4]) = r;
  }
}

// ---------- 8. cls/box heads: wave-per-output shuffle reduce ----------
__global__ __launch_bounds__(256) void fc_heads(
    const float* __restrict__ x,
    const float* __restrict__ wcls, const float* __restrict__ bcls,
    const float* __restrict__ wbox, const float* __restrict__ bbox,
    float* __restrict__ cls, float* __restrict__ box){
  int row = blockIdx.x, tid = threadIdx.x;
  __shared__ float xs[1024];
  *reinterpret_cast<float4*>(&xs[tid*4]) =
      *reinterpret_cast<const float4*>(&x[(size_t)row*1024 + tid*4]);
  __syncthreads();
  int w = tid >> 6, lane = tid & 63;
  for (int o=w; o<10; o+=4){
    float p = 0.f;
    if (o < 2){
      for (int k=lane;k<1024;k+=64) p += xs[k]*wcls[(size_t)k*2 + o];
    } else {
      int q = o-2;
      for (int k=lane;k<1024;k+=64) p += xs[k]*wbox[(size_t)k*8 + q];
    }
    #pragma unroll
    for (int off=32; off>0; off>>=1) p += __shfl_down(p, off);
    if (lane==0){
      if (o<2) cls[(size_t)row*2 + o] = p + bcls[o];
      else     box[(size_t)row*8 + (o-2)] = p + bbox[o-2];
    }
  }
}

// ---------- 9. per-batch postprocess (bitmask NMS in LDS) ----------
__global__ __launch_bounds__(1024) void postprocess_kernel(
    const float* __restrict__ cls, const float* __restrict__ boxd,
    const float* __restrict__ props, float* __restrict__ out){
  int b = blockIdx.x, tid = threadIdx.x;
  __shared__ float pb[512][4];
  __shared__ float sraw[512];
  __shared__ float s2a[512];
  __shared__ unsigned long long keys[512];
  __shared__ unsigned short order_[512];
  __shared__ unsigned char kval[512];
  __shared__ unsigned char korig[512];
  __shared__ unsigned long long pm[512][8];
  __shared__ volatile unsigned long long kw2[8];
  if (tid < 8) kw2[tid] = ~0ull;
  if (tid < 512){
    int r = b*512 + tid;
    float c0 = cls[(size_t)r*2+0], c1 = cls[(size_t)r*2+1];
    float mx = fmaxf(c0,c1);
    float e0 = expf(c0-mx), e1 = expf(c1-mx);
    float s = e1/(e0+e1);
    const float* pr = props + (size_t)r*4;
    float x1=pr[0], y1=pr[1], x2=pr[2], y2=pr[3];
    float w = x2-x1, h = y2-y1;
    float cx = x1 + 0.5f*w, cy = y1 + 0.5f*h;
    const float* dl = boxd + (size_t)r*8 + 4;
    float dx = dl[0]/10.f, dy = dl[1]/10.f;
    float dw = fminf(dl[2]/5.f, CLIPF), dh = fminf(dl[3]/5.f, CLIPF);
    float pcx = dx*w + cx, pcy = dy*h + cy;
    float pw = expf(dw)*w, ph = expf(dh)*h;
    float bx1 = fminf(fmaxf(pcx-0.5f*pw,0.f), IMGF);
    float by1 = fminf(fmaxf(pcy-0.5f*ph,0.f), IMGF);
    float bx2 = fminf(fmaxf(pcx+0.5f*pw,0.f), IMGF);
    float by2 = fminf(fmaxf(pcy+0.5f*ph,0.f), IMGF);
    pb[tid][0]=bx1; pb[tid][1]=by1; pb[tid][2]=bx2; pb[tid][3]=by2;
    bool valid = (s > 0.05f) && (bx2-bx1 >= 1e-2f) && (by2-by1 >= 1e-2f);
    sraw[tid]=s; kval[tid] = valid ? 1 : 0;
    float sm = valid ? s : -1e9f;
    keys[tid] = ((unsigned long long)fkey(sm)<<32) | (uint32_t)(~(uint32_t)tid);
  }
  __syncthreads();
  bitonic_desc(keys, 512, tid, 1024);
  if (tid < 512) order_[tid] = (unsigned short)(~(uint32_t)keys[tid]);
  __syncthreads();
  {
    int r = tid >> 1;
    int oi = order_[r];
    float ax1=pb[oi][0],ay1=pb[oi][1],ax2=pb[oi][2],ay2=pb[oi][3];
    float aa=(ax2-ax1)*(ay2-ay1);
    #pragma unroll
    for (int wo=0; wo<4; ++wo){
      int w = (tid&1)*4 + wo;
      unsigned long long m = 0ull;
      for (int jj=0;jj<64;jj++){
        int j = w*64 + jj;
        if (j > r){
          int oj = order_[j];
          float bx1=pb[oj][0],by1=pb[oj][1],bx2=pb[oj][2],by2=pb[oj][3];
          float ab=(bx2-bx1)*(by2-by1);
          float lx=fmaxf(ax1,bx1), ly=fmaxf(ay1,by1);
          float rx=fminf(ax2,bx2), ry=fminf(ay2,by2);
          float iw=fmaxf(rx-lx,0.f), ih=fmaxf(ry-ly,0.f);
          float inter=iw*ih;
          if (inter/(aa+ab-inter+1e-9f) > 0.5f) m |= (1ull<<jj);
        }
      }
      pm[r][w] = m;
    }
  }
  __syncthreads();
  if (tid < 8){
    for (int i=0;i<512;i++){
      unsigned long long kwv = kw2[i>>6];
      if ((kwv>>(i&63)) & 1ull) kw2[tid] &= ~pm[i][tid];
    }
  }
  __syncthreads();
  if (tid < 512){
    unsigned long long kwv = kw2[tid>>6];
    korig[order_[tid]] = (unsigned char)((kwv>>(tid&63)) & 1ull);
  }
  __syncthreads();
  if (tid < 512){
    float s2 = (korig[tid] && kval[tid]) ? sraw[tid] : 0.f;
    s2a[tid] = s2;
    keys[tid] = ((unsigned long long)fkey(s2)<<32) | (uint32_t)(~(uint32_t)tid);
  }
  __syncthreads();
  bitonic_desc(keys, 512, tid, 1024);
  if (tid < 100){
    uint32_t idx = ~(uint32_t)keys[tid];
    float ts = s2a[idx];
    float ok = (ts > 0.f) ? 1.f : 0.f;
    float* op = out + ((size_t)b*100 + tid)*6;
    op[0]=pb[idx][0]*ok; op[1]=pb[idx][1]*ok;
    op[2]=pb[idx][2]*ok; op[3]=pb[idx][3]*ok;
    op[4]=ts; op[5]=ok;
  }
}

// ---------- host launch ----------
extern "C" void kernel_launch(void* const* d_in, const int* in_sizes, int n_in,
                              void* d_out, int out_size, void* d_ws, size_t ws_size,
                              hipStream_t stream){
  (void)in_sizes; (void)n_in; (void)out_size; (void)ws_size;
  const float* feat[3] = {(const float*)d_in[0], (const float*)d_in[1], (const float*)d_in[2]};
  const float* rpn_conv_w = (const float*)d_in[3];
  const float* rpn_conv_b = (const float*)d_in[4];
  const float* rpn_cls_w  = (const float*)d_in[5];
  const float* rpn_cls_b  = (const float*)d_in[6];
  const float* rpn_box_w  = (const float*)d_in[7];
  const float* rpn_box_b  = (const float*)d_in[8];
  const float* fc1_w = (const float*)d_in[9];
  const float* fc1_b = (const float*)d_in[10];
  const float* fc2_w = (const float*)d_in[11];
  const float* fc2_b = (const float*)d_in[12];
  const float* cls_w = (const float*)d_in[13];
  const float* cls_b = (const float*)d_in[14];
  const float* box_w = (const float*)d_in[15];
  const float* box_b = (const float*)d_in[16];

  float* ws = (float*)d_ws;
  float* featT = ws;                        // 6,720,000 (live transpose..roi_align)
  float* fc1o  = ws;                        // 1,048,576 (after roi)
  float* fc2o  = ws + 1048576;              // 1,048,576
  float* clsb  = ws + 2097152;              //     2,048
  float* boxb  = ws + 2099200;              //     8,192
  float* parts = ws + 2107392;              // 4,194,304 -> ends 6,301,696
  float* props = ws + 6720000;              //     4,096
  float* roiX  = ws + 6724096;              // 12,845,056
  float* tP    = roiX;                      // 6,720,000 (conv output, position-major)
  float* objs       = roiX + 6720000;       //   393,750
  float* dels       = roiX + 7113750;       // 1,575,000
  float* lvl_boxes  = roiX + 8688750;       //    12,000
  float* lvl_scores = roiX + 8700750;       //     3,000
  float* nms_snb    = roiX + 8703750;       //    12,288
  int*   nms_order  = (int*)(roiX + 8716038);
  unsigned long long* nms_masks = (unsigned long long*)(roiX + 8719110);
  float* wrp2  = roiX + 8866568;            //    20,480
  float* wB    = roiX + 8887048;            //   589,824 (2304x256)

  const int HWs[3]   = {10000,2500,625};
  const int lvlOff[3]= {0,150000,187500};
  const int posOff[3]= {0,10000,12500};

  repack_heads_w<<<80, 256, 0, stream>>>(rpn_cls_w, rpn_box_w, wrp2);
  repack_wB<<<2304, 256, 0, stream>>>(rpn_conv_w, wB);

  for (int l=0;l<3;l++){
    dim3 gt((HWs[l]+31)/32, 8, 2);
    feat_transpose<<<gt, 256, 0, stream>>>(feat[l], featT, HWs[l], posOff[l]);
  }
  // conv3x3 as implicit GEMM, 128x64 tiles, XCD-chunked grid of 832
  gemm_conv64<<<832, 256, 0, stream>>>(featT, wB, rpn_conv_b, tP);
  for (int l=0;l<3;l++){
    dim3 gh((HWs[l]+63)/64, 2);
    rpn_heads_pm<<<gh, 256, 0, stream>>>(tP, wrp2, rpn_cls_b, rpn_box_b,
                                         objs, dels, HWs[l], posOff[l], lvlOff[l]);
  }
  rpn_topk_decode<<<dim3(3,2), 1024, 0, stream>>>(objs, dels, lvl_boxes, lvl_scores);
  nms_sort<<<2, 1024, 0, stream>>>(lvl_boxes, lvl_scores, nms_snb, nms_order);
  nms_mask<<<dim3(24,2), 256, 0, stream>>>(nms_snb, nms_masks);
  nms_scan_final<<<2, 1024, 0, stream>>>(nms_masks, nms_order, lvl_boxes, lvl_scores, props);
  roi_align<<<1024, 256, 0, stream>>>(featT, props, roiX);
  // fc1: [1024,12544] x [12544,1024], 128x64 tiles k32, split-K=4 (KC=3136)
  gemm64<<<dim3(16,8,4), 256, 0, stream>>>(roiX, fc1_w, parts, 1024, 1024, 12544, 3136);
  reduce_splitk<<<1024, 256, 0, stream>>>(parts, fc1_b, fc1o, 1024*1024, 1023, 1);
  // fc2: [1024,1024] x [1024,1024], split-K=4 (KC=256)
  gemm64<<<dim3(16,8,4), 256, 0, stream>>>(fc1o, fc2_w, parts, 1024, 1024, 1024, 256);
  reduce_splitk<<<1024, 256, 0, stream>>>(parts, fc2_b, fc2o, 1024*1024, 1023, 1);
  fc_heads<<<1024, 256, 0, stream>>>(fc2o, cls_w, cls_b, box_w, box_b, clsb, boxb);
  postprocess_kernel<<<2, 1024, 0, stream>>>(clsb, boxb, props, (float*)d_out);
}

// Round 11
// 1964.862 us; speedup vs baseline: 1.3851x; 1.3851x over previous
//
#include <hip/hip_runtime.h>
#include <hip/hip_bf16.h>
#include <stdint.h>

#define IMGF 800.0f
#define CLIPF 4.135166556742356f

typedef __attribute__((ext_vector_type(8))) short bf16x8;
typedef __attribute__((ext_vector_type(4))) float f32x4;
typedef __attribute__((ext_vector_type(8))) unsigned short u16x8;
#define MFMA32 __builtin_amdgcn_mfma_f32_16x16x32_bf16

// ---------- helpers ----------
__device__ __forceinline__ uint32_t fkey(float x){
  uint32_t b = __float_as_uint(x);
  return (b & 0x80000000u) ? ~b : (b | 0x80000000u);
}

__device__ __forceinline__ float bf2f(unsigned short h){
  return __uint_as_float(((uint32_t)h)<<16);
}

// 3-way bf16 split (RNE cascade) of 2 floats
__device__ __forceinline__ void split3x2(float x0, float x1,
    unsigned short&h0, unsigned short&h1, unsigned short&m0, unsigned short&m1,
    unsigned short&l0, unsigned short&l1){
  __hip_bfloat162 hb = __float22bfloat162_rn(make_float2(x0,x1));
  ushort2 hu = *reinterpret_cast<ushort2*>(&hb);
  float r0 = x0 - bf2f(hu.x), r1 = x1 - bf2f(hu.y);
  __hip_bfloat162 mb = __float22bfloat162_rn(make_float2(r0,r1));
  ushort2 mu = *reinterpret_cast<ushort2*>(&mb);
  float s0 = r0 - bf2f(mu.x), s1 = r1 - bf2f(mu.y);
  __hip_bfloat162 lb = __float22bfloat162_rn(make_float2(s0,s1));
  ushort2 lu = *reinterpret_cast<ushort2*>(&lb);
  h0=hu.x; h1=hu.y; m0=mu.x; m1=mu.y; l0=lu.x; l1=lu.y;
}

// descending bitonic sort of n (pow2) uint64 keys in LDS
__device__ void bitonic_desc(unsigned long long* k, int n, int tid, int nthr){
  for (int kk=2; kk<=n; kk<<=1){
    for (int j=kk>>1; j>0; j>>=1){
      __syncthreads();
      for (int i=tid; i<n; i+=nthr){
        int ixj = i ^ j;
        if (ixj > i){
          unsigned long long a = k[i], b = k[ixj];
          bool up = ((i & kk) == 0);
          if ((a < b) == up){ k[i]=b; k[ixj]=a; }
        }
      }
    }
  }
  __syncthreads();
}

// ---------- 0a. repack conv weights for implicit GEMM: wB[d*256+ic][oc] = w[oc][ic][d] ----------
__global__ __launch_bounds__(256) void repack_wB(
    const float* __restrict__ w, float* __restrict__ wB){
  int idx = blockIdx.x*256 + threadIdx.x;
  if (idx >= 2304*256) return;
  int oc = idx & 255; int rest = idx >> 8;
  int ic = rest & 255; int d = rest >> 8;
  wB[idx] = w[((size_t)oc*256 + ic)*9 + d];
}

// ---------- 0b. repack rpn head weights ----------
__global__ __launch_bounds__(256) void repack_heads_w(
    const float* __restrict__ wc, const float* __restrict__ wb, float* __restrict__ wrp2){
  int idx = blockIdx.x*256 + threadIdx.x;
  if (idx >= 4*256*20) return;
  int j = idx % 20; int rest = idx/20;
  int cc = rest & 255; int wv = rest >> 8;
  int o = wv + 4*j;
  float v = 0.f;
  if (j < 19 && o < 75) v = (o<15) ? wc[o*256+cc] : wb[(o-15)*256+cc];
  wrp2[idx] = v;
}

// ================= bf16x6 MFMA GEMM cores =================
// tile: BM=128, BN=64, BK=32; 4 waves (2m x 2n), wave tile 64x32 = 4x2 frags
// of 16x16x32 MFMA; x6 products (hi/mid/lo splits) => fp32-accurate.
// A in LDS row-major [128][40(pad)], B in LDS n-major [64][40].
// Frag maps: A lane: row=lane&15, k=(lane>>4)*8+[0..7]; B lane: col=lane&15,
// k=(lane>>4)*8+[0..7]; D lane,reg: row=(lane>>4)*4+reg, col=lane&15.

// ---------- 1. conv3x3 implicit GEMM (MFMA), grid 832 XCD-swizzled ----------
__global__ __launch_bounds__(256) void conv_mfma(
    const float* __restrict__ featT, const float* __restrict__ wB,
    const float* __restrict__ bias, float* __restrict__ tP){
  __shared__ unsigned short Ah[128*40], Amm[128*40], Al[128*40];
  __shared__ unsigned short Bh[64*40],  Bmm[64*40],  Bl[64*40];
  const int tid = threadIdx.x;
  const int bid = blockIdx.x;
  const int xcd = bid & 7, jb = bid >> 3;
  const int rt  = xcd*26 + (jb >> 2);
  const int bn  = (jb & 3) * 64;
  const int b = rt / 104;
  const int i = rt - b*104;
  int base, HW, W, posOff;
  if (i < 79)      { base = i*128;        HW = 10000; W = 100; posOff = 0; }
  else if (i < 99) { base = (i-79)*128;   HW = 2500;  W = 50;  posOff = 10000; }
  else             { base = (i-99)*128;   HW = 625;   W = 25;  posOff = 12500; }
  const int gRowBase = b*13125 + posOff;

  const int lane = tid & 63, wv = tid >> 6;
  const int wm = (wv>>1)*64, wn = (wv&1)*32;
  const int fr = lane & 15, fq = lane >> 4;

  // A staging: thread -> row=tid>>1 (0..127), 16 k at (tid&1)*16
  const int arow = tid >> 1;
  const int ak   = (tid & 1) * 16;
  const int apos = base + arow;
  const bool av  = apos < HW;
  const int ay = apos / W, ax = apos - ay*W;
  const float* arowp = featT + (size_t)(gRowBase + apos)*256;
  // B staging: thread -> n=tid&63, 8 k at (tid>>6)*8
  const int bnl = tid & 63, bk0 = (tid >> 6) * 8;

  f32x4 acc[4][2];
  #pragma unroll
  for (int mi=0;mi<4;mi++)
    #pragma unroll
    for (int ni=0;ni<2;ni++) acc[mi][ni] = (f32x4){0.f,0.f,0.f,0.f};

  float va[16], vb[8];
  int dcur = -1, shift = 0; bool okf = false;

  auto loadA = [&](int step){
    const int kb = step*32;
    const int d  = kb >> 8;
    if (d != dcur){
      dcur = d;
      const int q3 = (d*11) >> 5;
      const int dy = q3 - 1, dx = d - 3*q3 - 1;
      shift = (dy*W + dx)*256;
      okf = av && (unsigned)(ay+dy) < (unsigned)W && (unsigned)(ax+dx) < (unsigned)W;
    }
    const int ic0 = (kb & 255) + ak;
    if (okf){
      #pragma unroll
      for (int c=0;c<4;c++){
        float4 f = *reinterpret_cast<const float4*>(arowp + shift + ic0 + c*4);
        va[c*4+0]=f.x; va[c*4+1]=f.y; va[c*4+2]=f.z; va[c*4+3]=f.w;
      }
    } else {
      #pragma unroll
      for (int c=0;c<16;c++) va[c]=0.f;
    }
  };
  auto loadB = [&](int step){
    const int kb = step*32;
    #pragma unroll
    for (int j=0;j<8;j++) vb[j] = wB[(size_t)(kb + bk0 + j)*256 + bn + bnl];
  };
  auto storeAB = [&](){
    u16x8 h[2], m[2], l[2];
    #pragma unroll
    for (int c=0;c<2;c++)
      #pragma unroll
      for (int p=0;p<4;p++){
        unsigned short h0,h1,m0,m1,l0,l1;
        split3x2(va[c*8+p*2], va[c*8+p*2+1], h0,h1,m0,m1,l0,l1);
        h[c][p*2]=h0; h[c][p*2+1]=h1;
        m[c][p*2]=m0; m[c][p*2+1]=m1;
        l[c][p*2]=l0; l[c][p*2+1]=l1;
      }
    const int ao = arow*40 + ak;
    *reinterpret_cast<u16x8*>(&Ah [ao])   = h[0];
    *reinterpret_cast<u16x8*>(&Ah [ao+8]) = h[1];
    *reinterpret_cast<u16x8*>(&Amm[ao])   = m[0];
    *reinterpret_cast<u16x8*>(&Amm[ao+8]) = m[1];
    *reinterpret_cast<u16x8*>(&Al [ao])   = l[0];
    *reinterpret_cast<u16x8*>(&Al [ao+8]) = l[1];
    u16x8 hb, mb, lb;
    #pragma unroll
    for (int p=0;p<4;p++){
      unsigned short h0,h1,m0,m1,l0,l1;
      split3x2(vb[p*2], vb[p*2+1], h0,h1,m0,m1,l0,l1);
      hb[p*2]=h0; hb[p*2+1]=h1; mb[p*2]=m0; mb[p*2+1]=m1; lb[p*2]=l0; lb[p*2+1]=l1;
    }
    const int bo = bnl*40 + bk0;
    *reinterpret_cast<u16x8*>(&Bh [bo]) = hb;
    *reinterpret_cast<u16x8*>(&Bmm[bo]) = mb;
    *reinterpret_cast<u16x8*>(&Bl [bo]) = lb;
  };

  loadA(0); loadB(0);
  storeAB();
  __syncthreads();

  const int T = 72;   // 2304/32
  for (int t=0; t<T; ++t){
    if (t+1 < T){ loadA(t+1); loadB(t+1); }
    bf16x8 aH[4], aM[4], aL[4];
    #pragma unroll
    for (int mi=0;mi<4;mi++){
      const int ro = (wm + mi*16 + fr)*40 + fq*8;
      aH[mi] = *reinterpret_cast<const bf16x8*>(&Ah [ro]);
      aM[mi] = *reinterpret_cast<const bf16x8*>(&Amm[ro]);
      aL[mi] = *reinterpret_cast<const bf16x8*>(&Al [ro]);
    }
    #pragma unroll
    for (int ni=0;ni<2;ni++){
      const int co = (wn + ni*16 + fr)*40 + fq*8;
      bf16x8 bH = *reinterpret_cast<const bf16x8*>(&Bh [co]);
      bf16x8 bM = *reinterpret_cast<const bf16x8*>(&Bmm[co]);
      bf16x8 bL = *reinterpret_cast<const bf16x8*>(&Bl [co]);
      #pragma unroll
      for (int mi=0;mi<4;mi++){
        f32x4 a = acc[mi][ni];
        a = MFMA32(aL[mi], bH, a, 0,0,0);
        a = MFMA32(aM[mi], bM, a, 0,0,0);
        a = MFMA32(aH[mi], bL, a, 0,0,0);
        a = MFMA32(aM[mi], bH, a, 0,0,0);
        a = MFMA32(aH[mi], bM, a, 0,0,0);
        a = MFMA32(aH[mi], bH, a, 0,0,0);
        acc[mi][ni] = a;
      }
    }
    if (t+1 < T){
      __syncthreads();
      storeAB();
      __syncthreads();
    }
  }

  #pragma unroll
  for (int mi=0;mi<4;mi++){
    #pragma unroll
    for (int ni=0;ni<2;ni++){
      const int col = bn + wn + ni*16 + fr;
      const float bz = bias[col];
      #pragma unroll
      for (int r=0;r<4;r++){
        const int pos = base + wm + mi*16 + fq*4 + r;
        if (pos < HW)
          tP[(size_t)(gRowBase+pos)*256 + col] = fmaxf(acc[mi][ni][r] + bz, 0.f);
      }
    }
  }
}

// ---------- 7. fc GEMM (MFMA, split-K): part[kz] += A[.,kz-chunk]*B ----------
__global__ __launch_bounds__(256) void gemm_mfma(
    const float* __restrict__ Am, const float* __restrict__ Bm,
    float* __restrict__ part, int M, int N, int K, int KC){
  __shared__ unsigned short Ah[128*40], Amm[128*40], Al[128*40];
  __shared__ unsigned short Bh[64*40],  Bmm[64*40],  Bl[64*40];
  const int tid = threadIdx.x;
  const int bn = blockIdx.x*64, bm = blockIdx.y*128, kz = blockIdx.z;
  const int k0 = kz*KC;
  const int T = KC/32;

  const int lane = tid & 63, wv = tid >> 6;
  const int wm = (wv>>1)*64, wn = (wv&1)*32;
  const int fr = lane & 15, fq = lane >> 4;

  const int arow = tid >> 1;
  const int ak   = (tid & 1) * 16;
  const int bnl = tid & 63, bk0 = (tid >> 6) * 8;

  f32x4 acc[4][2];
  #pragma unroll
  for (int mi=0;mi<4;mi++)
    #pragma unroll
    for (int ni=0;ni<2;ni++) acc[mi][ni] = (f32x4){0.f,0.f,0.f,0.f};

  float va[16], vb[8];

  auto loadA = [&](int kb){
    const float* p = &Am[(size_t)(bm+arow)*K + kb + ak];
    #pragma unroll
    for (int c=0;c<4;c++){
      float4 f = *reinterpret_cast<const float4*>(p + c*4);
      va[c*4+0]=f.x; va[c*4+1]=f.y; va[c*4+2]=f.z; va[c*4+3]=f.w;
    }
  };
  auto loadB = [&](int kb){
    #pragma unroll
    for (int j=0;j<8;j++) vb[j] = Bm[(size_t)(kb + bk0 + j)*N + bn + bnl];
  };
  auto storeAB = [&](){
    u16x8 h[2], m[2], l[2];
    #pragma unroll
    for (int c=0;c<2;c++)
      #pragma unroll
      for (int p=0;p<4;p++){
        unsigned short h0,h1,m0,m1,l0,l1;
        split3x2(va[c*8+p*2], va[c*8+p*2+1], h0,h1,m0,m1,l0,l1);
        h[c][p*2]=h0; h[c][p*2+1]=h1;
        m[c][p*2]=m0; m[c][p*2+1]=m1;
        l[c][p*2]=l0; l[c][p*2+1]=l1;
      }
    const int ao = arow*40 + ak;
    *reinterpret_cast<u16x8*>(&Ah [ao])   = h[0];
    *reinterpret_cast<u16x8*>(&Ah [ao+8]) = h[1];
    *reinterpret_cast<u16x8*>(&Amm[ao])   = m[0];
    *reinterpret_cast<u16x8*>(&Amm[ao+8]) = m[1];
    *reinterpret_cast<u16x8*>(&Al [ao])   = l[0];
    *reinterpret_cast<u16x8*>(&Al [ao+8]) = l[1];
    u16x8 hb, mb, lb;
    #pragma unroll
    for (int p=0;p<4;p++){
      unsigned short h0,h1,m0,m1,l0,l1;
      split3x2(vb[p*2], vb[p*2+1], h0,h1,m0,m1,l0,l1);
      hb[p*2]=h0; hb[p*2+1]=h1; mb[p*2]=m0; mb[p*2+1]=m1; lb[p*2]=l0; lb[p*2+1]=l1;
    }
    const int bo = bnl*40 + bk0;
    *reinterpret_cast<u16x8*>(&Bh [bo]) = hb;
    *reinterpret_cast<u16x8*>(&Bmm[bo]) = mb;
    *reinterpret_cast<u16x8*>(&Bl [bo]) = lb;
  };

  loadA(k0); loadB(k0);
  storeAB();
  __syncthreads();

  for (int t=0; t<T; ++t){
    if (t+1 < T){ loadA(k0 + (t+1)*32); loadB(k0 + (t+1)*32); }
    bf16x8 aH[4], aM[4], aL[4];
    #pragma unroll
    for (int mi=0;mi<4;mi++){
      const int ro = (wm + mi*16 + fr)*40 + fq*8;
      aH[mi] = *reinterpret_cast<const bf16x8*>(&Ah [ro]);
      aM[mi] = *reinterpret_cast<const bf16x8*>(&Amm[ro]);
      aL[mi] = *reinterpret_cast<const bf16x8*>(&Al [ro]);
    }
    #pragma unroll
    for (int ni=0;ni<2;ni++){
      const int co = (wn + ni*16 + fr)*40 + fq*8;
      bf16x8 bH = *reinterpret_cast<const bf16x8*>(&Bh [co]);
      bf16x8 bM = *reinterpret_cast<const bf16x8*>(&Bmm[co]);
      bf16x8 bL = *reinterpret_cast<const bf16x8*>(&Bl [co]);
      #pragma unroll
      for (int mi=0;mi<4;mi++){
        f32x4 a = acc[mi][ni];
        a = MFMA32(aL[mi], bH, a, 0,0,0);
        a = MFMA32(aM[mi], bM, a, 0,0,0);
        a = MFMA32(aH[mi], bL, a, 0,0,0);
        a = MFMA32(aM[mi], bH, a, 0,0,0);
        a = MFMA32(aH[mi], bM, a, 0,0,0);
        a = MFMA32(aH[mi], bH, a, 0,0,0);
        acc[mi][ni] = a;
      }
    }
    if (t+1 < T){
      __syncthreads();
      storeAB();
      __syncthreads();
    }
  }

  float* pz = part + (size_t)kz*M*N;
  #pragma unroll
  for (int mi=0;mi<4;mi++){
    #pragma unroll
    for (int ni=0;ni<2;ni++){
      const int col = bn + wn + ni*16 + fr;
      #pragma unroll
      for (int r=0;r<4;r++){
        const int row = bm + wm + mi*16 + fq*4 + r;
        pz[(size_t)row*N + col] = acc[mi][ni][r];
      }
    }
  }
}

// ---------- 2. RPN 1x1 heads, position-major input ----------
__global__ __launch_bounds__(256) void rpn_heads_pm(
    const float* __restrict__ tP, const float* __restrict__ wrp2,
    const float* __restrict__ bc, const float* __restrict__ bb,
    float* __restrict__ objs, float* __restrict__ dels,
    int HW, int posOff, int lvlOff){
  int b = blockIdx.y;
  int p0 = blockIdx.x*64;
  int lane = threadIdx.x & 63;
  int wv = __builtin_amdgcn_readfirstlane(threadIdx.x >> 6);
  __shared__ float sh[64][129];
  float acc[19];
  #pragma unroll
  for (int j=0;j<19;j++) acc[j]=0.f;
  const float* tb = tP + (size_t)(b*13125 + posOff)*256;
  for (int half=0; half<2; ++half){
    __syncthreads();
    for (int idx=threadIdx.x; idx<64*128; idx+=256){
      int px = idx>>7, c = idx&127;
      int p = p0+px;
      sh[px][c] = (p<HW) ? tb[(size_t)p*256 + half*128 + c] : 0.f;
    }
    __syncthreads();
    for (int c=0;c<128;c++){
      float v = sh[lane][c];
      int cc = half*128 + c;
      const float* wr = wrp2 + ((size_t)wv*256 + cc)*20;
      #pragma unroll
      for (int j=0;j<19;j++){
        int o = wv + 4*j;
        if (o < 75) acc[j] += v*wr[j];
      }
    }
  }
  int p = p0 + lane;
  if (p < HW){
    #pragma unroll
    for (int j=0;j<19;j++){
      int o = wv + 4*j;
      if (o < 75){
        if (o < 15){
          objs[(size_t)b*196875 + lvlOff + (size_t)p*15 + o] = acc[j] + bc[o];
        } else {
          int q = o-15;
          dels[((size_t)b*196875 + lvlOff + (size_t)p*15 + (q>>2))*4 + (q&3)] = acc[j] + bb[q];
        }
      }
    }
  }
}

// ---------- 3. feats NCHW -> position-major channel-last ----------
__global__ __launch_bounds__(256) void feat_transpose(
    const float* __restrict__ f, float* __restrict__ ft, int HW, int posOff){
  __shared__ float tile[32][33];
  int b = blockIdx.z;
  int p0 = blockIdx.x*32, c0 = blockIdx.y*32;
  int tx = threadIdx.x & 31, ty = threadIdx.x >> 5;
  #pragma unroll
  for (int i=0;i<4;i++){
    int c = c0 + ty + i*8;
    int p = p0 + tx;
    tile[ty+i*8][tx] = (p<HW) ? f[((size_t)b*256 + c)*HW + p] : 0.f;
  }
  __syncthreads();
  #pragma unroll
  for (int i=0;i<4;i++){
    int p = p0 + ty + i*8;
    int c = c0 + tx;
    if (p < HW) ft[((size_t)b*13125 + posOff + p)*256 + c] = tile[tx][ty+i*8];
  }
}

// ---------- 4. per (batch,level) exact top-500 + decode ----------
__global__ __launch_bounds__(1024) void rpn_topk_decode(
    const float* __restrict__ objs, const float* __restrict__ dels,
    float* __restrict__ lvl_boxes, float* __restrict__ lvl_scores){
  const int lvl = blockIdx.x, b = blockIdx.y;
  const int Ns[3]   = {150000,37500,9375};
  const int Offs[3] = {0,150000,187500};
  const int Wl[3]   = {100,50,25};
  const float strid[3] = {8.f,16.f,32.f};
  const int N = Ns[lvl];
  const float* sc = objs + (size_t)b*196875 + Offs[lvl];
  __shared__ uint32_t hist[2048];
  __shared__ uint32_t sPrefix;
  __shared__ int sKrem;
  __shared__ int sCnt;
  __shared__ unsigned long long keys[2048];
  int tid = threadIdx.x;
  if (tid==0){ sKrem=500; sPrefix=0; }
  for (int i=tid;i<2048;i+=1024) hist[i]=0u;
  __syncthreads();
  for (int i=tid;i<N;i+=1024){ uint32_t u=fkey(sc[i]); atomicAdd(&hist[u>>21],1u); }
  __syncthreads();
  if (tid==0){
    int cum=0, K=sKrem;
    for (int i=2047;i>=0;i--){ int c=(int)hist[i]; if (cum+c>=K){ sPrefix=(uint32_t)i<<21; sKrem=K-cum; break;} cum+=c; }
  }
  __syncthreads();
  uint32_t pref1 = sPrefix;
  for (int i=tid;i<2048;i+=1024) hist[i]=0u;
  __syncthreads();
  for (int i=tid;i<N;i+=1024){ uint32_t u=fkey(sc[i]); if ((u & 0xFFE00000u)==pref1) atomicAdd(&hist[(u>>10)&0x7FFu],1u); }
  __syncthreads();
  if (tid==0){
    int cum=0, K=sKrem;
    for (int i=2047;i>=0;i--){ int c=(int)hist[i]; if (cum+c>=K){ sPrefix=pref1|((uint32_t)i<<10); sKrem=K-cum; break;} cum+=c; }
  }
  __syncthreads();
  uint32_t pref2 = sPrefix;
  for (int i=tid;i<2048;i+=1024) hist[i]=0u;
  __syncthreads();
  for (int i=tid;i<N;i+=1024){ uint32_t u=fkey(sc[i]); if ((u & 0xFFFFFC00u)==pref2) atomicAdd(&hist[u & 0x3FFu],1u); }
  __syncthreads();
  if (tid==0){
    int cum=0, K=sKrem;
    for (int i=1023;i>=0;i--){ int c=(int)hist[i]; if (cum+c>=K){ sPrefix=pref2|(uint32_t)i; break;} cum+=c; }
    sCnt=0;
  }
  __syncthreads();
  uint32_t T = sPrefix;
  for (int i=tid;i<N;i+=1024){
    uint32_t u=fkey(sc[i]);
    if (u>=T){ int k=atomicAdd(&sCnt,1); if (k<2048) keys[k]=((unsigned long long)u<<32)|(uint32_t)(~(uint32_t)i); }
  }
  __syncthreads();
  int m = sCnt; if (m>2048) m=2048;
  int n = 512; while (n<m) n<<=1;
  for (int i=tid;i<n;i+=1024) if (i>=m) keys[i]=0ull;
  __syncthreads();
  bitonic_desc(keys, n, tid, 1024);
  if (tid < 500){
    unsigned long long key = keys[tid];
    uint32_t idx = ~(uint32_t)(key & 0xFFFFFFFFull);
    float score = sc[idx];
    int p = idx/15, a = idx - p*15;
    int W = Wl[lvl];
    int hh = p / W, ww = p - hh*W;
    int r5 = a/5, s5 = a - r5*5;
    const float ratios[3] = {0.5f,1.0f,2.0f};
    const float scales[5] = {32.f,64.f,128.f,256.f,512.f};
    float hr = sqrtf(ratios[r5]); float wr = 1.0f/hr;
    float wsz = wr*scales[s5], hsz = hr*scales[s5];
    float sx = (float)ww*strid[lvl], sy = (float)hh*strid[lvl];
    float ax1 = sx - 0.5f*wsz, ay1 = sy - 0.5f*hsz;
    float ax2 = sx + 0.5f*wsz, ay2 = sy + 0.5f*hsz;
    const float* dl = dels + ((size_t)b*196875 + Offs[lvl] + idx)*4;
    float bw = ax2-ax1, bh = ay2-ay1;
    float cx = ax1 + 0.5f*bw, cy = ay1 + 0.5f*bh;
    float dx = dl[0], dy = dl[1];
    float dw = fminf(dl[2], CLIPF), dh = fminf(dl[3], CLIPF);
    float pcx = dx*bw + cx, pcy = dy*bh + cy;
    float pw = expf(dw)*bw, ph = expf(dh)*bh;
    float x1 = fminf(fmaxf(pcx - 0.5f*pw, 0.f), IMGF);
    float y1 = fminf(fmaxf(pcy - 0.5f*ph, 0.f), IMGF);
    float x2 = fminf(fmaxf(pcx + 0.5f*pw, 0.f), IMGF);
    float y2 = fminf(fmaxf(pcy + 0.5f*ph, 0.f), IMGF);
    int oidx = b*1500 + lvl*500 + tid;
    lvl_boxes[oidx*4+0]=x1; lvl_boxes[oidx*4+1]=y1;
    lvl_boxes[oidx*4+2]=x2; lvl_boxes[oidx*4+3]=y2;
    bool valid = (x2-x1 >= 1e-3f) && (y2-y1 >= 1e-3f);
    lvl_scores[oidx] = valid ? score : -1e9f;
  }
}

// ---------- 5a. NMS: sort by score ----------
__global__ __launch_bounds__(1024) void nms_sort(
    const float* __restrict__ lvl_boxes, const float* __restrict__ lvl_scores,
    float* __restrict__ snb, int* __restrict__ sorder){
  int b = blockIdx.x, tid = threadIdx.x;
  __shared__ unsigned long long keys[2048];
  const float* ls = lvl_scores + (size_t)b*1500;
  const float* lb = lvl_boxes + (size_t)b*1500*4;
  for (int i=tid;i<2048;i+=1024)
    keys[i] = (i<1500) ? (((unsigned long long)fkey(ls[i])<<32)|(uint32_t)(~(uint32_t)i)) : 0ull;
  __syncthreads();
  bitonic_desc(keys, 2048, tid, 1024);
  for (int r=tid;r<1536;r+=1024){
    if (r < 1500){
      int idx = (int)(~(uint32_t)keys[r]);
      sorder[(size_t)b*1536 + r] = idx;
      float offv = (float)(idx/500) * (IMGF + 16.0f);
      float* pp = snb + ((size_t)b*1536 + r)*4;
      pp[0]=lb[idx*4+0]+offv; pp[1]=lb[idx*4+1]+offv;
      pp[2]=lb[idx*4+2]+offv; pp[3]=lb[idx*4+3]+offv;
    } else {
      sorder[(size_t)b*1536 + r] = 0;
      float* pp = snb + ((size_t)b*1536 + r)*4;
      pp[0]=pp[1]=pp[2]=pp[3]=0.f;
    }
  }
}

// ---------- 5b. NMS: IoU suppression bitmask matrix ----------
__global__ __launch_bounds__(256) void nms_mask(
    const float* __restrict__ snb, unsigned long long* __restrict__ masks){
  int b = blockIdx.y;
  int i0 = blockIdx.x*64;
  __shared__ float sbx[1536][4];
  for (int t=threadIdx.x; t<1536*4; t+=256)
    sbx[t>>2][t&3] = snb[(size_t)b*1536*4 + t];
  __syncthreads();
  int il = threadIdx.x >> 2;
  int wq = threadIdx.x & 3;
  int i = i0 + il;
  float ax1=sbx[i][0], ay1=sbx[i][1], ax2=sbx[i][2], ay2=sbx[i][3];
  float aa=(ax2-ax1)*(ay2-ay1);
  #pragma unroll
  for (int wofs=0; wofs<6; ++wofs){
    int w = wq*6 + wofs;
    unsigned long long m = 0ull;
    if (i < 1500){
      for (int jj=0; jj<64; ++jj){
        int j = w*64 + jj;
        if (j > i && j < 1500){
          float bx1=sbx[j][0],by1=sbx[j][1],bx2=sbx[j][2],by2=sbx[j][3];
          float ab=(bx2-bx1)*(by2-by1);
          float lx=fmaxf(ax1,bx1), ly=fmaxf(ay1,by1);
          float rx=fminf(ax2,bx2), ry=fminf(ay2,by2);
          float iw=fmaxf(rx-lx,0.f), ih=fmaxf(ry-ly,0.f);
          float inter=iw*ih;
          if (inter/(aa+ab-inter+1e-9f) > 0.7f) m |= (1ull<<jj);
        }
      }
    }
    masks[((size_t)b*1536 + i)*24 + w] = m;
  }
}

// ---------- 5c. NMS: serial bitmask scan + final top-512 gather ----------
__global__ __launch_bounds__(1024) void nms_scan_final(
    const unsigned long long* __restrict__ masks, const int* __restrict__ sorder,
    const float* __restrict__ lvl_boxes, const float* __restrict__ lvl_scores,
    float* __restrict__ props){
  int b = blockIdx.x, tid = threadIdx.x;
  __shared__ unsigned long long cm[128][24];
  __shared__ volatile unsigned long long keepw[24];
  __shared__ unsigned char korig[1536];
  __shared__ unsigned long long keys[2048];
  if (tid < 24) keepw[tid] = (tid==23) ? ((1ull<<28)-1ull) : ~0ull;
  for (int c=0; c<12; ++c){
    __syncthreads();
    for (int t=tid; t<128*24; t+=1024)
      cm[t/24][t%24] = masks[((size_t)b*1536 + c*128)*24 + t];
    __syncthreads();
    if (tid < 24){
      int lim = (c==11) ? 84 : 128;
      for (int il=0; il<lim; ++il){
        int i = c*128 + il;
        unsigned long long kw = keepw[i>>6];
        if ((kw>>(i&63)) & 1ull) keepw[tid] &= ~cm[il][tid];
      }
    }
  }
  __syncthreads();
  for (int r=tid; r<1500; r+=1024){
    unsigned long long kw = keepw[r>>6];
    korig[sorder[(size_t)b*1536 + r]] = (unsigned char)((kw>>(r&63)) & 1ull);
  }
  __syncthreads();
  const float* ls = lvl_scores + (size_t)b*1500;
  const float* lb = lvl_boxes + (size_t)b*1500*4;
  for (int i=tid;i<2048;i+=1024){
    if (i<1500){
      float s = korig[i] ? ls[i] : -1e9f;
      keys[i] = ((unsigned long long)fkey(s)<<32)|(uint32_t)(~(uint32_t)i);
    } else keys[i]=0ull;
  }
  __syncthreads();
  bitonic_desc(keys, 2048, tid, 1024);
  for (int j=tid;j<512;j+=1024){
    int idx = (int)(~(uint32_t)keys[j]);
    float* pp = props + ((size_t)b*512 + j)*4;
    pp[0]=lb[idx*4+0]; pp[1]=lb[idx*4+1]; pp[2]=lb[idx*4+2]; pp[3]=lb[idx*4+3];
  }
}

// ---------- 6. ROI align ----------
__global__ __launch_bounds__(256) void roi_align(
    const float* __restrict__ featT, const float* __restrict__ props,
    float* __restrict__ roiX){
  int blk = blockIdx.x;
  int b = blk >> 9, n = blk & 511;
  const float* box = props + ((size_t)b*512 + n)*4;
  float x1=box[0], y1=box[1], x2=box[2], y2=box[3];
  float area = fmaxf(x2-x1,0.f)*fmaxf(y2-y1,0.f);
  float kf = floorf(4.0f + log2f(sqrtf(area)/224.0f + 1e-6f));
  kf = fminf(fmaxf(kf, 3.f), 5.f);
  int lvl = (int)kf - 3;
  const int Wl[3] = {100,50,25};
  const int posOff[3] = {0,10000,12500};
  const float strid[3] = {8.f,16.f,32.f};
  float scl = 1.0f/strid[lvl];
  float hw = (float)Wl[lvl];
  float rx1 = x1*scl, ry1 = y1*scl;
  float rw = fmaxf(x2*scl - rx1, 1.0f), rh = fmaxf(y2*scl - ry1, 1.0f);
  float bw = rw/7.0f, bh = rh/7.0f;
  __shared__ int sIdx[196][4];
  __shared__ float sW[196][4];
  int t = threadIdx.x;
  if (t < 196){
    int bin = t>>2, s = t&3;
    int py = bin/7, px = bin - py*7;
    int sy = s>>1, sx = s&1;
    float sgy = ((float)sy + 0.5f)*0.5f, sgx = ((float)sx + 0.5f)*0.5f;
    float Y = ry1 + ((float)py + sgy)*bh;
    float X = rx1 + ((float)px + sgx)*bw;
    Y = fminf(fmaxf(Y,0.f), hw-1.0f);
    X = fminf(fmaxf(X,0.f), hw-1.0f);
    float y0 = floorf(Y), x0 = floorf(X);
    float ly = Y-y0, lx = X-x0;
    int y0i=(int)y0, x0i=(int)x0;
    int hi = Wl[lvl]-1;
    int y1i = (y0i+1<hi)?(y0i+1):hi;
    int x1i = (x0i+1<hi)?(x0i+1):hi;
    int W = Wl[lvl];
    int base = b*13125 + posOff[lvl];
    sIdx[t][0] = (base + y0i*W + x0i)*256;
    sIdx[t][1] = (base + y0i*W + x1i)*256;
    sIdx[t][2] = (base + y1i*W + x0i)*256;
    sIdx[t][3] = (base + y1i*W + x1i)*256;
    sW[t][0]=(1.f-ly)*(1.f-lx); sW[t][1]=(1.f-ly)*lx;
    sW[t][2]=ly*(1.f-lx);       sW[t][3]=ly*lx;
  }
  __syncthreads();
  int c = t;
  float* orow = roiX + ((size_t)b*512 + n)*12544 + (size_t)c*49;
  for (int bin=0;bin<49;bin++){
    float acc = 0.f;
    #pragma unroll
    for (int s=0;s<4;s++){
      int tt = bin*4+s;
      acc += sW[tt][0]*featT[sIdx[tt][0]+c] + sW[tt][1]*featT[sIdx[tt][1]+c]
           + sW[tt][2]*featT[sIdx[tt][2]+c] + sW[tt][3]*featT[sIdx[tt][3]+c];
    }
    orow[bin] = acc*0.25f;
  }
}

// reduce SPLITK=4 partials + bias (+relu). N must be pow2.
__global__ __launch_bounds__(256) void reduce_splitk(
    const float* __restrict__ part, const float* __restrict__ bias,
    float* __restrict__ out, int MN, int Nmask, int relu){
  int i4 = (blockIdx.x*256 + threadIdx.x)*4;
  if (i4 < MN){
    float4 s0 = *reinterpret_cast<const float4*>(&part[i4]);
    float4 s1 = *reinterpret_cast<const float4*>(&part[(size_t)MN + i4]);
    float4 s2 = *reinterpret_cast<const float4*>(&part[(size_t)2*MN + i4]);
    float4 s3 = *reinterpret_cast<const float4*>(&part[(size_t)3*MN + i4]);
    float4 bb = *reinterpret_cast<const float4*>(&bias[i4 & Nmask]);
    float4 r;
    r.x = s0.x+s1.x+s2.x+s3.x+bb.x;
    r.y = s0.y+s1.y+s2.y+s3.y+bb.y;
    r.z = s0.z+s1.z+s2.z+s3.z+bb.z;
    r.w = s0.w+s1.w+s2.w+s3.w+bb.w;
    if (relu){ r.x=fmaxf(r.x,0.f); r.y=fmaxf(r.y,0.f); r.z=fmaxf(r.z,0.f); r.w=fmaxf(r.w,0.f); }
    *reinterpret_cast<float4*>(&out[i4]) = r;
  }
}

// ---------- 8. cls/box heads ----------
__global__ __launch_bounds__(256) void fc_heads(
    const float* __restrict__ x,
    const float* __restrict__ wcls, const float* __restrict__ bcls,
    const float* __restrict__ wbox, const float* __restrict__ bbox,
    float* __restrict__ cls, float* __restrict__ box){
  int row = blockIdx.x, tid = threadIdx.x;
  __shared__ float xs[1024];
  *reinterpret_cast<float4*>(&xs[tid*4]) =
      *reinterpret_cast<const float4*>(&x[(size_t)row*1024 + tid*4]);
  __syncthreads();
  int w = tid >> 6, lane = tid & 63;
  for (int o=w; o<10; o+=4){
    float p = 0.f;
    if (o < 2){
      for (int k=lane;k<1024;k+=64) p += xs[k]*wcls[(size_t)k*2 + o];
    } else {
      int q = o-2;
      for (int k=lane;k<1024;k+=64) p += xs[k]*wbox[(size_t)k*8 + q];
    }
    #pragma unroll
    for (int off=32; off>0; off>>=1) p += __shfl_down(p, off);
    if (lane==0){
      if (o<2) cls[(size_t)row*2 + o] = p + bcls[o];
      else     box[(size_t)row*8 + (o-2)] = p + bbox[o-2];
    }
  }
}

// ---------- 9. per-batch postprocess ----------
__global__ __launch_bounds__(1024) void postprocess_kernel(
    const float* __restrict__ cls, const float* __restrict__ boxd,
    const float* __restrict__ props, float* __restrict__ out){
  int b = blockIdx.x, tid = threadIdx.x;
  __shared__ float pb[512][4];
  __shared__ float sraw[512];
  __shared__ float s2a[512];
  __shared__ unsigned long long keys[512];
  __shared__ unsigned short order_[512];
  __shared__ unsigned char kval[512];
  __shared__ unsigned char korig[512];
  __shared__ unsigned long long pm[512][8];
  __shared__ volatile unsigned long long kw2[8];
  if (tid < 8) kw2[tid] = ~0ull;
  if (tid < 512){
    int r = b*512 + tid;
    float c0 = cls[(size_t)r*2+0], c1 = cls[(size_t)r*2+1];
    float mx = fmaxf(c0,c1);
    float e0 = expf(c0-mx), e1 = expf(c1-mx);
    float s = e1/(e0+e1);
    const float* pr = props + (size_t)r*4;
    float x1=pr[0], y1=pr[1], x2=pr[2], y2=pr[3];
    float w = x2-x1, h = y2-y1;
    float cx = x1 + 0.5f*w, cy = y1 + 0.5f*h;
    const float* dl = boxd + (size_t)r*8 + 4;
    float dx = dl[0]/10.f, dy = dl[1]/10.f;
    float dw = fminf(dl[2]/5.f, CLIPF), dh = fminf(dl[3]/5.f, CLIPF);
    float pcx = dx*w + cx, pcy = dy*h + cy;
    float pw = expf(dw)*w, ph = expf(dh)*h;
    float bx1 = fminf(fmaxf(pcx-0.5f*pw,0.f), IMGF);
    float by1 = fminf(fmaxf(pcy-0.5f*ph,0.f), IMGF);
    float bx2 = fminf(fmaxf(pcx+0.5f*pw,0.f), IMGF);
    float by2 = fminf(fmaxf(pcy+0.5f*ph,0.f), IMGF);
    pb[tid][0]=bx1; pb[tid][1]=by1; pb[tid][2]=bx2; pb[tid][3]=by2;
    bool valid = (s > 0.05f) && (bx2-bx1 >= 1e-2f) && (by2-by1 >= 1e-2f);
    sraw[tid]=s; kval[tid] = valid ? 1 : 0;
    float sm = valid ? s : -1e9f;
    keys[tid] = ((unsigned long long)fkey(sm)<<32) | (uint32_t)(~(uint32_t)tid);
  }
  __syncthreads();
  bitonic_desc(keys, 512, tid, 1024);
  if (tid < 512) order_[tid] = (unsigned short)(~(uint32_t)keys[tid]);
  __syncthreads();
  {
    int r = tid >> 1;
    int oi = order_[r];
    float ax1=pb[oi][0],ay1=pb[oi][1],ax2=pb[oi][2],ay2=pb[oi][3];
    float aa=(ax2-ax1)*(ay2-ay1);
    #pragma unroll
    for (int wo=0; wo<4; ++wo){
      int w = (tid&1)*4 + wo;
      unsigned long long m = 0ull;
      for (int jj=0;jj<64;jj++){
        int j = w*64 + jj;
        if (j > r){
          int oj = order_[j];
          float bx1=pb[oj][0],by1=pb[oj][1],bx2=pb[oj][2],by2=pb[oj][3];
          float ab=(bx2-bx1)*(by2-by1);
          float lx=fmaxf(ax1,bx1), ly=fmaxf(ay1,by1);
          float rx=fminf(ax2,bx2), ry=fminf(ay2,by2);
          float iw=fmaxf(rx-lx,0.f), ih=fmaxf(ry-ly,0.f);
          float inter=iw*ih;
          if (inter/(aa+ab-inter+1e-9f) > 0.5f) m |= (1ull<<jj);
        }
      }
      pm[r][w] = m;
    }
  }
  __syncthreads();
  if (tid < 8){
    for (int i=0;i<512;i++){
      unsigned long long kwv = kw2[i>>6];
      if ((kwv>>(i&63)) & 1ull) kw2[tid] &= ~pm[i][tid];
    }
  }
  __syncthreads();
  if (tid < 512){
    unsigned long long kwv = kw2[tid>>6];
    korig[order_[tid]] = (unsigned char)((kwv>>(tid&63)) & 1ull);
  }
  __syncthreads();
  if (tid < 512){
    float s2 = (korig[tid] && kval[tid]) ? sraw[tid] : 0.f;
    s2a[tid] = s2;
    keys[tid] = ((unsigned long long)fkey(s2)<<32) | (uint32_t)(~(uint32_t)tid);
  }
  __syncthreads();
  bitonic_desc(keys, 512, tid, 1024);
  if (tid < 100){
    uint32_t idx = ~(uint32_t)keys[tid];
    float ts = s2a[idx];
    float ok = (ts > 0.f) ? 1.f : 0.f;
    float* op = out + ((size_t)b*100 + tid)*6;
    op[0]=pb[idx][0]*ok; op[1]=pb[idx][1]*ok;
    op[2]=pb[idx][2]*ok; op[3]=pb[idx][3]*ok;
    op[4]=ts; op[5]=ok;
  }
}

// ---------- host launch ----------
extern "C" void kernel_launch(void* const* d_in, const int* in_sizes, int n_in,
                              void* d_out, int out_size, void* d_ws, size_t ws_size,
                              hipStream_t stream){
  (void)in_sizes; (void)n_in; (void)out_size; (void)ws_size;
  const float* feat[3] = {(const float*)d_in[0], (const float*)d_in[1], (const float*)d_in[2]};
  const float* rpn_conv_w = (const float*)d_in[3];
  const float* rpn_conv_b = (const float*)d_in[4];
  const float* rpn_cls_w  = (const float*)d_in[5];
  const float* rpn_cls_b  = (const float*)d_in[6];
  const float* rpn_box_w  = (const float*)d_in[7];
  const float* rpn_box_b  = (const float*)d_in[8];
  const float* fc1_w = (const float*)d_in[9];
  const float* fc1_b = (const float*)d_in[10];
  const float* fc2_w = (const float*)d_in[11];
  const float* fc2_b = (const float*)d_in[12];
  const float* cls_w = (const float*)d_in[13];
  const float* cls_b = (const float*)d_in[14];
  const float* box_w = (const float*)d_in[15];
  const float* box_b = (const float*)d_in[16];

  float* ws = (float*)d_ws;
  float* featT = ws;                        // 6,720,000 (live transpose..roi_align)
  float* fc1o  = ws;                        // 1,048,576 (after roi)
  float* fc2o  = ws + 1048576;              // 1,048,576
  float* clsb  = ws + 2097152;              //     2,048
  float* boxb  = ws + 2099200;              //     8,192
  float* parts = ws + 2107392;              // 4,194,304 -> ends 6,301,696
  float* props = ws + 6720000;              //     4,096
  float* roiX  = ws + 6724096;              // 12,845,056
  float* tP    = roiX;                      // 6,720,000 (conv output, position-major)
  float* objs       = roiX + 6720000;       //   393,750
  float* dels       = roiX + 7113750;       // 1,575,000
  float* lvl_boxes  = roiX + 8688750;       //    12,000
  float* lvl_scores = roiX + 8700750;       //     3,000
  float* nms_snb    = roiX + 8703750;       //    12,288
  int*   nms_order  = (int*)(roiX + 8716038);
  unsigned long long* nms_masks = (unsigned long long*)(roiX + 8719110);
  float* wrp2  = roiX + 8866568;            //    20,480
  float* wB    = roiX + 8887048;            //   589,824 (2304x256)

  const int HWs[3]   = {10000,2500,625};
  const int lvlOff[3]= {0,150000,187500};
  const int posOff[3]= {0,10000,12500};

  repack_heads_w<<<80, 256, 0, stream>>>(rpn_cls_w, rpn_box_w, wrp2);
  repack_wB<<<2304, 256, 0, stream>>>(rpn_conv_w, wB);

  for (int l=0;l<3;l++){
    dim3 gt((HWs[l]+31)/32, 8, 2);
    feat_transpose<<<gt, 256, 0, stream>>>(feat[l], featT, HWs[l], posOff[l]);
  }
  // conv3x3 as implicit GEMM on matrix cores (bf16x6), XCD-swizzled grid 832
  conv_mfma<<<832, 256, 0, stream>>>(featT, wB, rpn_conv_b, tP);
  for (int l=0;l<3;l++){
    dim3 gh((HWs[l]+63)/64, 2);
    rpn_heads_pm<<<gh, 256, 0, stream>>>(tP, wrp2, rpn_cls_b, rpn_box_b,
                                         objs, dels, HWs[l], posOff[l], lvlOff[l]);
  }
  rpn_topk_decode<<<dim3(3,2), 1024, 0, stream>>>(objs, dels, lvl_boxes, lvl_scores);
  nms_sort<<<2, 1024, 0, stream>>>(lvl_boxes, lvl_scores, nms_snb, nms_order);
  nms_mask<<<dim3(24,2), 256, 0, stream>>>(nms_snb, nms_masks);
  nms_scan_final<<<2, 1024, 0, stream>>>(nms_masks, nms_order, lvl_boxes, lvl_scores, props);
  roi_align<<<1024, 256, 0, stream>>>(featT, props, roiX);
  // fc1: [1024,12544]x[12544,1024] MFMA bf16x6, split-K 4 (KC=3136, 98 steps)
  gemm_mfma<<<dim3(16,8,4), 256, 0, stream>>>(roiX, fc1_w, parts, 1024, 1024, 12544, 3136);
  reduce_splitk<<<1024, 256, 0, stream>>>(parts, fc1_b, fc1o, 1024*1024, 1023, 1);
  // fc2: [1024,1024]x[1024,1024] MFMA bf16x6, split-K 4 (KC=256, 8 steps)
  gemm_mfma<<<dim3(16,8,4), 256, 0, stream>>>(fc1o, fc2_w, parts, 1024, 1024, 1024, 256);
  reduce_splitk<<<1024, 256, 0, stream>>>(parts, fc2_b, fc2o, 1024*1024, 1023, 1);
  fc_heads<<<1024, 256, 0, stream>>>(fc2o, cls_w, cls_b, box_w, box_b, clsb, boxb);
  postprocess_kernel<<<2, 1024, 0, stream>>>(clsb, boxb, props, (float*)d_out);
}

// Round 12
// 1831.048 us; speedup vs baseline: 1.4864x; 1.0731x over previous
//
#include <hip/hip_runtime.h>
#include <hip/hip_bf16.h>
#include <stdint.h>

#define IMGF 800.0f
#define CLIPF 4.135166556742356f

typedef __attribute__((ext_vector_type(8))) short bf16x8;
typedef __attribute__((ext_vector_type(4))) float f32x4;
typedef __attribute__((ext_vector_type(8))) unsigned short u16x8;
#define MFMA32 __builtin_amdgcn_mfma_f32_16x16x32_bf16

// ---------- helpers ----------
__device__ __forceinline__ uint32_t fkey(float x){
  uint32_t b = __float_as_uint(x);
  return (b & 0x80000000u) ? ~b : (b | 0x80000000u);
}

__device__ __forceinline__ float bf2f(unsigned short h){
  return __uint_as_float(((uint32_t)h)<<16);
}

// 3-way bf16 split (RNE cascade) of 2 floats
__device__ __forceinline__ void split3x2(float x0, float x1,
    unsigned short&h0, unsigned short&h1, unsigned short&m0, unsigned short&m1,
    unsigned short&l0, unsigned short&l1){
  __hip_bfloat162 hb = __float22bfloat162_rn(make_float2(x0,x1));
  ushort2 hu = *reinterpret_cast<ushort2*>(&hb);
  float r0 = x0 - bf2f(hu.x), r1 = x1 - bf2f(hu.y);
  __hip_bfloat162 mb = __float22bfloat162_rn(make_float2(r0,r1));
  ushort2 mu = *reinterpret_cast<ushort2*>(&mb);
  float s0 = r0 - bf2f(mu.x), s1 = r1 - bf2f(mu.y);
  __hip_bfloat162 lb = __float22bfloat162_rn(make_float2(s0,s1));
  ushort2 lu = *reinterpret_cast<ushort2*>(&lb);
  h0=hu.x; h1=hu.y; m0=mu.x; m1=mu.y; l0=lu.x; l1=lu.y;
}

// descending bitonic sort of n (pow2) uint64 keys in LDS
__device__ void bitonic_desc(unsigned long long* k, int n, int tid, int nthr){
  for (int kk=2; kk<=n; kk<<=1){
    for (int j=kk>>1; j>0; j>>=1){
      __syncthreads();
      for (int i=tid; i<n; i+=nthr){
        int ixj = i ^ j;
        if (ixj > i){
          unsigned long long a = k[i], b = k[ixj];
          bool up = ((i & kk) == 0);
          if ((a < b) == up){ k[i]=b; k[ixj]=a; }
        }
      }
    }
  }
  __syncthreads();
}

// ---------- 0a. repack conv weights for implicit GEMM ----------
__global__ __launch_bounds__(256) void repack_wB(
    const float* __restrict__ w, float* __restrict__ wB){
  int idx = blockIdx.x*256 + threadIdx.x;
  if (idx >= 2304*256) return;
  int oc = idx & 255; int rest = idx >> 8;
  int ic = rest & 255; int d = rest >> 8;
  wB[idx] = w[((size_t)oc*256 + ic)*9 + d];
}

// ---------- 0b. repack rpn head weights ----------
__global__ __launch_bounds__(256) void repack_heads_w(
    const float* __restrict__ wc, const float* __restrict__ wb, float* __restrict__ wrp2){
  int idx = blockIdx.x*256 + threadIdx.x;
  if (idx >= 4*256*20) return;
  int j = idx % 20; int rest = idx/20;
  int cc = rest & 255; int wv = rest >> 8;
  int o = wv + 4*j;
  float v = 0.f;
  if (j < 19 && o < 75) v = (o<15) ? wc[o*256+cc] : wb[(o-15)*256+cc];
  wrp2[idx] = v;
}

// ---------- 1. conv3x3 implicit GEMM (MFMA bf16x6), grid 832 XCD-swizzled ----------
__global__ __launch_bounds__(256) void conv_mfma(
    const float* __restrict__ featT, const float* __restrict__ wB,
    const float* __restrict__ bias, float* __restrict__ tP){
  __shared__ unsigned short Ah[128*40], Amm[128*40], Al[128*40];
  __shared__ unsigned short Bh[64*40],  Bmm[64*40],  Bl[64*40];
  const int tid = threadIdx.x;
  const int bid = blockIdx.x;
  const int xcd = bid & 7, jb = bid >> 3;
  const int rt  = xcd*26 + (jb >> 2);
  const int bn  = (jb & 3) * 64;
  const int b = rt / 104;
  const int i = rt - b*104;
  int base, HW, W, posOff;
  if (i < 79)      { base = i*128;        HW = 10000; W = 100; posOff = 0; }
  else if (i < 99) { base = (i-79)*128;   HW = 2500;  W = 50;  posOff = 10000; }
  else             { base = (i-99)*128;   HW = 625;   W = 25;  posOff = 12500; }
  const int gRowBase = b*13125 + posOff;

  const int lane = tid & 63, wv = tid >> 6;
  const int wm = (wv>>1)*64, wn = (wv&1)*32;
  const int fr = lane & 15, fq = lane >> 4;

  const int arow = tid >> 1;
  const int ak   = (tid & 1) * 16;
  const int apos = base + arow;
  const bool av  = apos < HW;
  const int ay = apos / W, ax = apos - ay*W;
  const float* arowp = featT + (size_t)(gRowBase + apos)*256;
  const int bnl = tid & 63, bk0 = (tid >> 6) * 8;

  f32x4 acc[4][2];
  #pragma unroll
  for (int mi=0;mi<4;mi++)
    #pragma unroll
    for (int ni=0;ni<2;ni++) acc[mi][ni] = (f32x4){0.f,0.f,0.f,0.f};

  float va[16], vb[8];
  int dcur = -1, shift = 0; bool okf = false;

  auto loadA = [&](int step){
    const int kb = step*32;
    const int d  = kb >> 8;
    if (d != dcur){
      dcur = d;
      const int q3 = (d*11) >> 5;
      const int dy = q3 - 1, dx = d - 3*q3 - 1;
      shift = (dy*W + dx)*256;
      okf = av && (unsigned)(ay+dy) < (unsigned)W && (unsigned)(ax+dx) < (unsigned)W;
    }
    const int ic0 = (kb & 255) + ak;
    if (okf){
      #pragma unroll
      for (int c=0;c<4;c++){
        float4 f = *reinterpret_cast<const float4*>(arowp + shift + ic0 + c*4);
        va[c*4+0]=f.x; va[c*4+1]=f.y; va[c*4+2]=f.z; va[c*4+3]=f.w;
      }
    } else {
      #pragma unroll
      for (int c=0;c<16;c++) va[c]=0.f;
    }
  };
  auto loadB = [&](int step){
    const int kb = step*32;
    #pragma unroll
    for (int j=0;j<8;j++) vb[j] = wB[(size_t)(kb + bk0 + j)*256 + bn + bnl];
  };
  auto storeAB = [&](){
    u16x8 h[2], m[2], l[2];
    #pragma unroll
    for (int c=0;c<2;c++)
      #pragma unroll
      for (int p=0;p<4;p++){
        unsigned short h0,h1,m0,m1,l0,l1;
        split3x2(va[c*8+p*2], va[c*8+p*2+1], h0,h1,m0,m1,l0,l1);
        h[c][p*2]=h0; h[c][p*2+1]=h1;
        m[c][p*2]=m0; m[c][p*2+1]=m1;
        l[c][p*2]=l0; l[c][p*2+1]=l1;
      }
    const int ao = arow*40 + ak;
    *reinterpret_cast<u16x8*>(&Ah [ao])   = h[0];
    *reinterpret_cast<u16x8*>(&Ah [ao+8]) = h[1];
    *reinterpret_cast<u16x8*>(&Amm[ao])   = m[0];
    *reinterpret_cast<u16x8*>(&Amm[ao+8]) = m[1];
    *reinterpret_cast<u16x8*>(&Al [ao])   = l[0];
    *reinterpret_cast<u16x8*>(&Al [ao+8]) = l[1];
    u16x8 hb, mb, lb;
    #pragma unroll
    for (int p=0;p<4;p++){
      unsigned short h0,h1,m0,m1,l0,l1;
      split3x2(vb[p*2], vb[p*2+1], h0,h1,m0,m1,l0,l1);
      hb[p*2]=h0; hb[p*2+1]=h1; mb[p*2]=m0; mb[p*2+1]=m1; lb[p*2]=l0; lb[p*2+1]=l1;
    }
    const int bo = bnl*40 + bk0;
    *reinterpret_cast<u16x8*>(&Bh [bo]) = hb;
    *reinterpret_cast<u16x8*>(&Bmm[bo]) = mb;
    *reinterpret_cast<u16x8*>(&Bl [bo]) = lb;
  };

  loadA(0); loadB(0);
  storeAB();
  __syncthreads();

  const int T = 72;
  for (int t=0; t<T; ++t){
    if (t+1 < T){ loadA(t+1); loadB(t+1); }
    bf16x8 aH[4], aM[4], aL[4];
    #pragma unroll
    for (int mi=0;mi<4;mi++){
      const int ro = (wm + mi*16 + fr)*40 + fq*8;
      aH[mi] = *reinterpret_cast<const bf16x8*>(&Ah [ro]);
      aM[mi] = *reinterpret_cast<const bf16x8*>(&Amm[ro]);
      aL[mi] = *reinterpret_cast<const bf16x8*>(&Al [ro]);
    }
    #pragma unroll
    for (int ni=0;ni<2;ni++){
      const int co = (wn + ni*16 + fr)*40 + fq*8;
      bf16x8 bH = *reinterpret_cast<const bf16x8*>(&Bh [co]);
      bf16x8 bM = *reinterpret_cast<const bf16x8*>(&Bmm[co]);
      bf16x8 bL = *reinterpret_cast<const bf16x8*>(&Bl [co]);
      #pragma unroll
      for (int mi=0;mi<4;mi++){
        f32x4 a = acc[mi][ni];
        a = MFMA32(aL[mi], bH, a, 0,0,0);
        a = MFMA32(aM[mi], bM, a, 0,0,0);
        a = MFMA32(aH[mi], bL, a, 0,0,0);
        a = MFMA32(aM[mi], bH, a, 0,0,0);
        a = MFMA32(aH[mi], bM, a, 0,0,0);
        a = MFMA32(aH[mi], bH, a, 0,0,0);
        acc[mi][ni] = a;
      }
    }
    if (t+1 < T){
      __syncthreads();
      storeAB();
      __syncthreads();
    }
  }

  #pragma unroll
  for (int mi=0;mi<4;mi++){
    #pragma unroll
    for (int ni=0;ni<2;ni++){
      const int col = bn + wn + ni*16 + fr;
      const float bz = bias[col];
      #pragma unroll
      for (int r=0;r<4;r++){
        const int pos = base + wm + mi*16 + fq*4 + r;
        if (pos < HW)
          tP[(size_t)(gRowBase+pos)*256 + col] = fmaxf(acc[mi][ni][r] + bz, 0.f);
      }
    }
  }
}

// ---------- 7. fc GEMM (MFMA bf16x6, split-K) ----------
__global__ __launch_bounds__(256) void gemm_mfma(
    const float* __restrict__ Am, const float* __restrict__ Bm,
    float* __restrict__ part, int M, int N, int K, int KC){
  __shared__ unsigned short Ah[128*40], Amm[128*40], Al[128*40];
  __shared__ unsigned short Bh[64*40],  Bmm[64*40],  Bl[64*40];
  const int tid = threadIdx.x;
  const int bn = blockIdx.x*64, bm = blockIdx.y*128, kz = blockIdx.z;
  const int k0 = kz*KC;
  const int T = KC/32;

  const int lane = tid & 63, wv = tid >> 6;
  const int wm = (wv>>1)*64, wn = (wv&1)*32;
  const int fr = lane & 15, fq = lane >> 4;

  const int arow = tid >> 1;
  const int ak   = (tid & 1) * 16;
  const int bnl = tid & 63, bk0 = (tid >> 6) * 8;

  f32x4 acc[4][2];
  #pragma unroll
  for (int mi=0;mi<4;mi++)
    #pragma unroll
    for (int ni=0;ni<2;ni++) acc[mi][ni] = (f32x4){0.f,0.f,0.f,0.f};

  float va[16], vb[8];

  auto loadA = [&](int kb){
    const float* p = &Am[(size_t)(bm+arow)*K + kb + ak];
    #pragma unroll
    for (int c=0;c<4;c++){
      float4 f = *reinterpret_cast<const float4*>(p + c*4);
      va[c*4+0]=f.x; va[c*4+1]=f.y; va[c*4+2]=f.z; va[c*4+3]=f.w;
    }
  };
  auto loadB = [&](int kb){
    #pragma unroll
    for (int j=0;j<8;j++) vb[j] = Bm[(size_t)(kb + bk0 + j)*N + bn + bnl];
  };
  auto storeAB = [&](){
    u16x8 h[2], m[2], l[2];
    #pragma unroll
    for (int c=0;c<2;c++)
      #pragma unroll
      for (int p=0;p<4;p++){
        unsigned short h0,h1,m0,m1,l0,l1;
        split3x2(va[c*8+p*2], va[c*8+p*2+1], h0,h1,m0,m1,l0,l1);
        h[c][p*2]=h0; h[c][p*2+1]=h1;
        m[c][p*2]=m0; m[c][p*2+1]=m1;
        l[c][p*2]=l0; l[c][p*2+1]=l1;
      }
    const int ao = arow*40 + ak;
    *reinterpret_cast<u16x8*>(&Ah [ao])   = h[0];
    *reinterpret_cast<u16x8*>(&Ah [ao+8]) = h[1];
    *reinterpret_cast<u16x8*>(&Amm[ao])   = m[0];
    *reinterpret_cast<u16x8*>(&Amm[ao+8]) = m[1];
    *reinterpret_cast<u16x8*>(&Al [ao])   = l[0];
    *reinterpret_cast<u16x8*>(&Al [ao+8]) = l[1];
    u16x8 hb, mb, lb;
    #pragma unroll
    for (int p=0;p<4;p++){
      unsigned short h0,h1,m0,m1,l0,l1;
      split3x2(vb[p*2], vb[p*2+1], h0,h1,m0,m1,l0,l1);
      hb[p*2]=h0; hb[p*2+1]=h1; mb[p*2]=m0; mb[p*2+1]=m1; lb[p*2]=l0; lb[p*2+1]=l1;
    }
    const int bo = bnl*40 + bk0;
    *reinterpret_cast<u16x8*>(&Bh [bo]) = hb;
    *reinterpret_cast<u16x8*>(&Bmm[bo]) = mb;
    *reinterpret_cast<u16x8*>(&Bl [bo]) = lb;
  };

  loadA(k0); loadB(k0);
  storeAB();
  __syncthreads();

  for (int t=0; t<T; ++t){
    if (t+1 < T){ loadA(k0 + (t+1)*32); loadB(k0 + (t+1)*32); }
    bf16x8 aH[4], aM[4], aL[4];
    #pragma unroll
    for (int mi=0;mi<4;mi++){
      const int ro = (wm + mi*16 + fr)*40 + fq*8;
      aH[mi] = *reinterpret_cast<const bf16x8*>(&Ah [ro]);
      aM[mi] = *reinterpret_cast<const bf16x8*>(&Amm[ro]);
      aL[mi] = *reinterpret_cast<const bf16x8*>(&Al [ro]);
    }
    #pragma unroll
    for (int ni=0;ni<2;ni++){
      const int co = (wn + ni*16 + fr)*40 + fq*8;
      bf16x8 bH = *reinterpret_cast<const bf16x8*>(&Bh [co]);
      bf16x8 bM = *reinterpret_cast<const bf16x8*>(&Bmm[co]);
      bf16x8 bL = *reinterpret_cast<const bf16x8*>(&Bl [co]);
      #pragma unroll
      for (int mi=0;mi<4;mi++){
        f32x4 a = acc[mi][ni];
        a = MFMA32(aL[mi], bH, a, 0,0,0);
        a = MFMA32(aM[mi], bM, a, 0,0,0);
        a = MFMA32(aH[mi], bL, a, 0,0,0);
        a = MFMA32(aM[mi], bH, a, 0,0,0);
        a = MFMA32(aH[mi], bM, a, 0,0,0);
        a = MFMA32(aH[mi], bH, a, 0,0,0);
        acc[mi][ni] = a;
      }
    }
    if (t+1 < T){
      __syncthreads();
      storeAB();
      __syncthreads();
    }
  }

  float* pz = part + (size_t)kz*M*N;
  #pragma unroll
  for (int mi=0;mi<4;mi++){
    #pragma unroll
    for (int ni=0;ni<2;ni++){
      const int col = bn + wn + ni*16 + fr;
      #pragma unroll
      for (int r=0;r<4;r++){
        const int row = bm + wm + mi*16 + fq*4 + r;
        pz[(size_t)row*N + col] = acc[mi][ni][r];
      }
    }
  }
}

// ---------- 2. RPN 1x1 heads ----------
__global__ __launch_bounds__(256) void rpn_heads_pm(
    const float* __restrict__ tP, const float* __restrict__ wrp2,
    const float* __restrict__ bc, const float* __restrict__ bb,
    float* __restrict__ objs, float* __restrict__ dels,
    int HW, int posOff, int lvlOff){
  int b = blockIdx.y;
  int p0 = blockIdx.x*64;
  int lane = threadIdx.x & 63;
  int wv = __builtin_amdgcn_readfirstlane(threadIdx.x >> 6);
  __shared__ float sh[64][129];
  float acc[19];
  #pragma unroll
  for (int j=0;j<19;j++) acc[j]=0.f;
  const float* tb = tP + (size_t)(b*13125 + posOff)*256;
  for (int half=0; half<2; ++half){
    __syncthreads();
    for (int idx=threadIdx.x; idx<64*128; idx+=256){
      int px = idx>>7, c = idx&127;
      int p = p0+px;
      sh[px][c] = (p<HW) ? tb[(size_t)p*256 + half*128 + c] : 0.f;
    }
    __syncthreads();
    for (int c=0;c<128;c++){
      float v = sh[lane][c];
      int cc = half*128 + c;
      const float* wr = wrp2 + ((size_t)wv*256 + cc)*20;
      #pragma unroll
      for (int j=0;j<19;j++){
        int o = wv + 4*j;
        if (o < 75) acc[j] += v*wr[j];
      }
    }
  }
  int p = p0 + lane;
  if (p < HW){
    #pragma unroll
    for (int j=0;j<19;j++){
      int o = wv + 4*j;
      if (o < 75){
        if (o < 15){
          objs[(size_t)b*196875 + lvlOff + (size_t)p*15 + o] = acc[j] + bc[o];
        } else {
          int q = o-15;
          dels[((size_t)b*196875 + lvlOff + (size_t)p*15 + (q>>2))*4 + (q&3)] = acc[j] + bb[q];
        }
      }
    }
  }
}

// ---------- 3. feats NCHW -> position-major channel-last ----------
__global__ __launch_bounds__(256) void feat_transpose(
    const float* __restrict__ f, float* __restrict__ ft, int HW, int posOff){
  __shared__ float tile[32][33];
  int b = blockIdx.z;
  int p0 = blockIdx.x*32, c0 = blockIdx.y*32;
  int tx = threadIdx.x & 31, ty = threadIdx.x >> 5;
  #pragma unroll
  for (int i=0;i<4;i++){
    int c = c0 + ty + i*8;
    int p = p0 + tx;
    tile[ty+i*8][tx] = (p<HW) ? f[((size_t)b*256 + c)*HW + p] : 0.f;
  }
  __syncthreads();
  #pragma unroll
  for (int i=0;i<4;i++){
    int p = p0 + ty + i*8;
    int c = c0 + tx;
    if (p < HW) ft[((size_t)b*13125 + posOff + p)*256 + c] = tile[tx][ty+i*8];
  }
}

// ================= parallel exact top-500 pipeline =================
__device__ __forceinline__ void tk_params(int pl, int& b, int& lvl, int& N, int& off){
  b = pl/3; lvl = pl - b*3;
  const int Ns[3]   = {150000,37500,9375};
  const int Offs[3] = {0,150000,187500};
  N = Ns[lvl]; off = Offs[lvl];
}

// in-place suffix-sum over s[0..NB), then find B: suf(B)>=K>suf(B+1).
__device__ void suffix_select(uint32_t* s, int NB, int K, int tid,
                              int* outB, int* outK){
  for (int step=1; step<NB; step<<=1){
    uint32_t v[4]; int c=0;
    for (int i=tid;i<NB;i+=1024){ v[c++] = s[i] + ((i+step<NB)?s[i+step]:0u); }
    __syncthreads();
    c=0;
    for (int i=tid;i<NB;i+=1024) s[i]=v[c++];
    __syncthreads();
  }
  for (int i=tid;i<NB;i+=1024){
    int sufi = (int)s[i];
    int sufn = (i+1<NB)?(int)s[i+1]:0;
    if (sufi >= K && sufn < K){ *outB = i; *outK = K - sufn; }
  }
  __syncthreads();
}

__global__ __launch_bounds__(256) void tk_zero(uint32_t* __restrict__ buf, int n){
  int i = blockIdx.x*256 + threadIdx.x;
  if (i < n) buf[i] = 0u;
}

// hist of top-12 bits; grid (8, 6)
__global__ __launch_bounds__(1024) void tk_hist1(
    const float* __restrict__ objs, uint32_t* __restrict__ gh1){
  __shared__ uint32_t h[4096];
  int pl = blockIdx.y, b, lvl, N, off;
  tk_params(pl,b,lvl,N,off);
  const float* sc = objs + (size_t)b*196875 + off;
  int tid = threadIdx.x;
  for (int i=tid;i<4096;i+=1024) h[i]=0u;
  __syncthreads();
  int cs = (N+7)>>3;
  int s0 = blockIdx.x*cs, s1 = s0+cs; if (s1>N) s1=N;
  for (int i=s0+tid;i<s1;i+=1024) atomicAdd(&h[fkey(sc[i])>>20],1u);
  __syncthreads();
  uint32_t* g = gh1 + pl*4096;
  for (int i=tid;i<4096;i+=1024) if(h[i]) atomicAdd(&g[i],h[i]);
}

// refine bits [19:8] within boundary bin B1; grid (8,6)
__global__ __launch_bounds__(1024) void tk_hist2(
    const float* __restrict__ objs, const uint32_t* __restrict__ gh1,
    uint32_t* __restrict__ gh2){
  __shared__ uint32_t s[4096];
  __shared__ int sB, sK;
  int pl = blockIdx.y, b, lvl, N, off;
  tk_params(pl,b,lvl,N,off);
  const float* sc = objs + (size_t)b*196875 + off;
  int tid = threadIdx.x;
  for (int i=tid;i<4096;i+=1024) s[i]=gh1[pl*4096+i];
  __syncthreads();
  suffix_select(s,4096,500,tid,&sB,&sK);
  const uint32_t B1 = (uint32_t)sB;
  __syncthreads();
  for (int i=tid;i<4096;i+=1024) s[i]=0u;
  __syncthreads();
  int cs = (N+7)>>3;
  int s0 = blockIdx.x*cs, s1 = s0+cs; if (s1>N) s1=N;
  for (int i=s0+tid;i<s1;i+=1024){
    uint32_t u = fkey(sc[i]);
    if ((u>>20)==B1) atomicAdd(&s[(u>>8)&0xFFFu],1u);
  }
  __syncthreads();
  uint32_t* g = gh2 + pl*4096;
  for (int i=tid;i<4096;i+=1024) if(s[i]) atomicAdd(&g[i],s[i]);
}

// refine bits [7:0]; grid (8,6)
__global__ __launch_bounds__(1024) void tk_hist3(
    const float* __restrict__ objs, const uint32_t* __restrict__ gh1,
    const uint32_t* __restrict__ gh2, uint32_t* __restrict__ gh3){
  __shared__ uint32_t s[4096];
  __shared__ int sB, sK;
  int pl = blockIdx.y, b, lvl, N, off;
  tk_params(pl,b,lvl,N,off);
  const float* sc = objs + (size_t)b*196875 + off;
  int tid = threadIdx.x;
  for (int i=tid;i<4096;i+=1024) s[i]=gh1[pl*4096+i];
  __syncthreads();
  suffix_select(s,4096,500,tid,&sB,&sK);
  const uint32_t B1 = (uint32_t)sB; const int k1 = sK;
  __syncthreads();
  for (int i=tid;i<4096;i+=1024) s[i]=gh2[pl*4096+i];
  __syncthreads();
  suffix_select(s,4096,k1,tid,&sB,&sK);
  const uint32_t B2 = (uint32_t)sB;
  const uint32_t pref24 = (B1<<12)|B2;
  __syncthreads();
  for (int i=tid;i<256;i+=1024) s[i]=0u;
  __syncthreads();
  int cs = (N+7)>>3;
  int s0 = blockIdx.x*cs, s1 = s0+cs; if (s1>N) s1=N;
  for (int i=s0+tid;i<s1;i+=1024){
    uint32_t u = fkey(sc[i]);
    if ((u>>8)==pref24) atomicAdd(&s[u & 0xFFu],1u);
  }
  __syncthreads();
  uint32_t* g = gh3 + pl*256;
  for (int i=tid;i<256;i+=1024) if(s[i]) atomicAdd(&g[i],s[i]);
}

// compact candidates (u >= exact 32-bit threshold); grid (8,6)
__global__ __launch_bounds__(1024) void tk_compact(
    const float* __restrict__ objs, const uint32_t* __restrict__ gh1,
    const uint32_t* __restrict__ gh2, const uint32_t* __restrict__ gh3,
    int* __restrict__ candCnt, unsigned long long* __restrict__ cand){
  __shared__ uint32_t s[4096];
  __shared__ int sB, sK;
  int pl = blockIdx.y, b, lvl, N, off;
  tk_params(pl,b,lvl,N,off);
  const float* sc = objs + (size_t)b*196875 + off;
  int tid = threadIdx.x;
  for (int i=tid;i<4096;i+=1024) s[i]=gh1[pl*4096+i];
  __syncthreads();
  suffix_select(s,4096,500,tid,&sB,&sK);
  const uint32_t B1 = (uint32_t)sB; const int k1 = sK;
  __syncthreads();
  for (int i=tid;i<4096;i+=1024) s[i]=gh2[pl*4096+i];
  __syncthreads();
  suffix_select(s,4096,k1,tid,&sB,&sK);
  const uint32_t B2 = (uint32_t)sB; const int k2 = sK;
  __syncthreads();
  for (int i=tid;i<256;i+=1024) s[i]=gh3[pl*256+i];
  __syncthreads();
  suffix_select(s,256,k2,tid,&sB,&sK);
  const uint32_t B3 = (uint32_t)sB;
  const uint32_t T = (B1<<20)|(B2<<8)|B3;
  int cs = (N+7)>>3;
  int s0 = blockIdx.x*cs, s1 = s0+cs; if (s1>N) s1=N;
  unsigned long long* cp = cand + (size_t)pl*4096;
  for (int i=s0+tid;i<s1;i+=1024){
    uint32_t u = fkey(sc[i]);
    if (u >= T){
      int pos = atomicAdd(&candCnt[pl], 1);
      if (pos < 4096)
        cp[pos] = ((unsigned long long)u<<32) | (uint32_t)(~(uint32_t)i);
    }
  }
}

// sort candidates, take top-500, decode boxes; grid (3,2)
__global__ __launch_bounds__(1024) void tk_sortdecode(
    const float* __restrict__ objs, const float* __restrict__ dels,
    const int* __restrict__ candCnt, const unsigned long long* __restrict__ cand,
    float* __restrict__ lvl_boxes, float* __restrict__ lvl_scores){
  const int lvl = blockIdx.x, b = blockIdx.y;
  const int pl = b*3 + lvl;
  const int Offs[3] = {0,150000,187500};
  const int Wl[3]   = {100,50,25};
  const float strid[3] = {8.f,16.f,32.f};
  const float* sc = objs + (size_t)b*196875 + Offs[lvl];
  __shared__ unsigned long long keys[4096];
  int tid = threadIdx.x;
  int m = candCnt[pl]; if (m > 4096) m = 4096;
  int n = 512; while (n < m) n <<= 1;
  const unsigned long long* cp = cand + (size_t)pl*4096;
  for (int i=tid;i<n;i+=1024) keys[i] = (i<m) ? cp[i] : 0ull;
  __syncthreads();
  bitonic_desc(keys, n, tid, 1024);
  if (tid < 500){
    unsigned long long key = keys[tid];
    uint32_t idx = ~(uint32_t)(key & 0xFFFFFFFFull);
    float score = sc[idx];
    int p = idx/15, a = idx - p*15;
    int W = Wl[lvl];
    int hh = p / W, ww = p - hh*W;
    int r5 = a/5, s5 = a - r5*5;
    const float ratios[3] = {0.5f,1.0f,2.0f};
    const float scales[5] = {32.f,64.f,128.f,256.f,512.f};
    float hr = sqrtf(ratios[r5]); float wr = 1.0f/hr;
    float wsz = wr*scales[s5], hsz = hr*scales[s5];
    float sx = (float)ww*strid[lvl], sy = (float)hh*strid[lvl];
    float ax1 = sx - 0.5f*wsz, ay1 = sy - 0.5f*hsz;
    float ax2 = sx + 0.5f*wsz, ay2 = sy + 0.5f*hsz;
    const float* dl = dels + ((size_t)b*196875 + Offs[lvl] + idx)*4;
    float bw = ax2-ax1, bh = ay2-ay1;
    float cx = ax1 + 0.5f*bw, cy = ay1 + 0.5f*bh;
    float dx = dl[0], dy = dl[1];
    float dw = fminf(dl[2], CLIPF), dh = fminf(dl[3], CLIPF);
    float pcx = dx*bw + cx, pcy = dy*bh + cy;
    float pw = expf(dw)*bw, ph = expf(dh)*bh;
    float x1 = fminf(fmaxf(pcx - 0.5f*pw, 0.f), IMGF);
    float y1 = fminf(fmaxf(pcy - 0.5f*ph, 0.f), IMGF);
    float x2 = fminf(fmaxf(pcx + 0.5f*pw, 0.f), IMGF);
    float y2 = fminf(fmaxf(pcy + 0.5f*ph, 0.f), IMGF);
    int oidx = b*1500 + lvl*500 + tid;
    lvl_boxes[oidx*4+0]=x1; lvl_boxes[oidx*4+1]=y1;
    lvl_boxes[oidx*4+2]=x2; lvl_boxes[oidx*4+3]=y2;
    bool valid = (x2-x1 >= 1e-3f) && (y2-y1 >= 1e-3f);
    lvl_scores[oidx] = valid ? score : -1e9f;
  }
}

// ---------- 5a. NMS: sort by score ----------
__global__ __launch_bounds__(1024) void nms_sort(
    const float* __restrict__ lvl_boxes, const float* __restrict__ lvl_scores,
    float* __restrict__ snb, int* __restrict__ sorder){
  int b = blockIdx.x, tid = threadIdx.x;
  __shared__ unsigned long long keys[2048];
  const float* ls = lvl_scores + (size_t)b*1500;
  const float* lb = lvl_boxes + (size_t)b*1500*4;
  for (int i=tid;i<2048;i+=1024)
    keys[i] = (i<1500) ? (((unsigned long long)fkey(ls[i])<<32)|(uint32_t)(~(uint32_t)i)) : 0ull;
  __syncthreads();
  bitonic_desc(keys, 2048, tid, 1024);
  for (int r=tid;r<1536;r+=1024){
    if (r < 1500){
      int idx = (int)(~(uint32_t)keys[r]);
      sorder[(size_t)b*1536 + r] = idx;
      float offv = (float)(idx/500) * (IMGF + 16.0f);
      float* pp = snb + ((size_t)b*1536 + r)*4;
      pp[0]=lb[idx*4+0]+offv; pp[1]=lb[idx*4+1]+offv;
      pp[2]=lb[idx*4+2]+offv; pp[3]=lb[idx*4+3]+offv;
    } else {
      sorder[(size_t)b*1536 + r] = 0;
      float* pp = snb + ((size_t)b*1536 + r)*4;
      pp[0]=pp[1]=pp[2]=pp[3]=0.f;
    }
  }
}

// ---------- 5b. NMS: IoU suppression bitmask matrix ----------
__global__ __launch_bounds__(256) void nms_mask(
    const float* __restrict__ snb, unsigned long long* __restrict__ masks){
  int b = blockIdx.y;
  int i0 = blockIdx.x*64;
  __shared__ float sbx[1536][4];
  for (int t=threadIdx.x; t<1536*4; t+=256)
    sbx[t>>2][t&3] = snb[(size_t)b*1536*4 + t];
  __syncthreads();
  int il = threadIdx.x >> 2;
  int wq = threadIdx.x & 3;
  int i = i0 + il;
  float ax1=sbx[i][0], ay1=sbx[i][1], ax2=sbx[i][2], ay2=sbx[i][3];
  float aa=(ax2-ax1)*(ay2-ay1);
  #pragma unroll
  for (int wofs=0; wofs<6; ++wofs){
    int w = wq*6 + wofs;
    unsigned long long m = 0ull;
    if (i < 1500){
      for (int jj=0; jj<64; ++jj){
        int j = w*64 + jj;
        if (j > i && j < 1500){
          float bx1=sbx[j][0],by1=sbx[j][1],bx2=sbx[j][2],by2=sbx[j][3];
          float ab=(bx2-bx1)*(by2-by1);
          float lx=fmaxf(ax1,bx1), ly=fmaxf(ay1,by1);
          float rx=fminf(ax2,bx2), ry=fminf(ay2,by2);
          float iw=fmaxf(rx-lx,0.f), ih=fmaxf(ry-ly,0.f);
          float inter=iw*ih;
          if (inter/(aa+ab-inter+1e-9f) > 0.7f) m |= (1ull<<jj);
        }
      }
    }
    masks[((size_t)b*1536 + i)*24 + w] = m;
  }
}

// ---------- 5c. NMS: serial bitmask scan + final top-512 gather ----------
__global__ __launch_bounds__(1024) void nms_scan_final(
    const unsigned long long* __restrict__ masks, const int* __restrict__ sorder,
    const float* __restrict__ lvl_boxes, const float* __restrict__ lvl_scores,
    float* __restrict__ props){
  int b = blockIdx.x, tid = threadIdx.x;
  __shared__ unsigned long long cm[128][24];
  __shared__ volatile unsigned long long keepw[24];
  __shared__ unsigned char korig[1536];
  __shared__ unsigned long long keys[2048];
  if (tid < 24) keepw[tid] = (tid==23) ? ((1ull<<28)-1ull) : ~0ull;
  for (int c=0; c<12; ++c){
    __syncthreads();
    for (int t=tid; t<128*24; t+=1024)
      cm[t/24][t%24] = masks[((size_t)b*1536 + c*128)*24 + t];
    __syncthreads();
    if (tid < 24){
      int lim = (c==11) ? 84 : 128;
      for (int il=0; il<lim; ++il){
        int i = c*128 + il;
        unsigned long long kw = keepw[i>>6];
        if ((kw>>(i&63)) & 1ull) keepw[tid] &= ~cm[il][tid];
      }
    }
  }
  __syncthreads();
  for (int r=tid; r<1500; r+=1024){
    unsigned long long kw = keepw[r>>6];
    korig[sorder[(size_t)b*1536 + r]] = (unsigned char)((kw>>(r&63)) & 1ull);
  }
  __syncthreads();
  const float* ls = lvl_scores + (size_t)b*1500;
  const float* lb = lvl_boxes + (size_t)b*1500*4;
  for (int i=tid;i<2048;i+=1024){
    if (i<1500){
      float s = korig[i] ? ls[i] : -1e9f;
      keys[i] = ((unsigned long long)fkey(s)<<32)|(uint32_t)(~(uint32_t)i);
    } else keys[i]=0ull;
  }
  __syncthreads();
  bitonic_desc(keys, 2048, tid, 1024);
  for (int j=tid;j<512;j+=1024){
    int idx = (int)(~(uint32_t)keys[j]);
    float* pp = props + ((size_t)b*512 + j)*4;
    pp[0]=lb[idx*4+0]; pp[1]=lb[idx*4+1]; pp[2]=lb[idx*4+2]; pp[3]=lb[idx*4+3];
  }
}

// ---------- 6. ROI align ----------
__global__ __launch_bounds__(256) void roi_align(
    const float* __restrict__ featT, const float* __restrict__ props,
    float* __restrict__ roiX){
  int blk = blockIdx.x;
  int b = blk >> 9, n = blk & 511;
  const float* box = props + ((size_t)b*512 + n)*4;
  float x1=box[0], y1=box[1], x2=box[2], y2=box[3];
  float area = fmaxf(x2-x1,0.f)*fmaxf(y2-y1,0.f);
  float kf = floorf(4.0f + log2f(sqrtf(area)/224.0f + 1e-6f));
  kf = fminf(fmaxf(kf, 3.f), 5.f);
  int lvl = (int)kf - 3;
  const int Wl[3] = {100,50,25};
  const int posOff[3] = {0,10000,12500};
  const float strid[3] = {8.f,16.f,32.f};
  float scl = 1.0f/strid[lvl];
  float hw = (float)Wl[lvl];
  float rx1 = x1*scl, ry1 = y1*scl;
  float rw = fmaxf(x2*scl - rx1, 1.0f), rh = fmaxf(y2*scl - ry1, 1.0f);
  float bw = rw/7.0f, bh = rh/7.0f;
  __shared__ int sIdx[196][4];
  __shared__ float sW[196][4];
  int t = threadIdx.x;
  if (t < 196){
    int bin = t>>2, s = t&3;
    int py = bin/7, px = bin - py*7;
    int sy = s>>1, sx = s&1;
    float sgy = ((float)sy + 0.5f)*0.5f, sgx = ((float)sx + 0.5f)*0.5f;
    float Y = ry1 + ((float)py + sgy)*bh;
    float X = rx1 + ((float)px + sgx)*bw;
    Y = fminf(fmaxf(Y,0.f), hw-1.0f);
    X = fminf(fmaxf(X,0.f), hw-1.0f);
    float y0 = floorf(Y), x0 = floorf(X);
    float ly = Y-y0, lx = X-x0;
    int y0i=(int)y0, x0i=(int)x0;
    int hi = Wl[lvl]-1;
    int y1i = (y0i+1<hi)?(y0i+1):hi;
    int x1i = (x0i+1<hi)?(x0i+1):hi;
    int W = Wl[lvl];
    int base = b*13125 + posOff[lvl];
    sIdx[t][0] = (base + y0i*W + x0i)*256;
    sIdx[t][1] = (base + y0i*W + x1i)*256;
    sIdx[t][2] = (base + y1i*W + x0i)*256;
    sIdx[t][3] = (base + y1i*W + x1i)*256;
    sW[t][0]=(1.f-ly)*(1.f-lx); sW[t][1]=(1.f-ly)*lx;
    sW[t][2]=ly*(1.f-lx);       sW[t][3]=ly*lx;
  }
  __syncthreads();
  int c = t;
  float* orow = roiX + ((size_t)b*512 + n)*12544 + (size_t)c*49;
  for (int bin=0;bin<49;bin++){
    float acc = 0.f;
    #pragma unroll
    for (int s=0;s<4;s++){
      int tt = bin*4+s;
      acc += sW[tt][0]*featT[sIdx[tt][0]+c] + sW[tt][1]*featT[sIdx[tt][1]+c]
           + sW[tt][2]*featT[sIdx[tt][2]+c] + sW[tt][3]*featT[sIdx[tt][3]+c];
    }
    orow[bin] = acc*0.25f;
  }
}

// reduce SPLITK=4 partials + bias (+relu)
__global__ __launch_bounds__(256) void reduce_splitk(
    const float* __restrict__ part, const float* __restrict__ bias,
    float* __restrict__ out, int MN, int Nmask, int relu){
  int i4 = (blockIdx.x*256 + threadIdx.x)*4;
  if (i4 < MN){
    float4 s0 = *reinterpret_cast<const float4*>(&part[i4]);
    float4 s1 = *reinterpret_cast<const float4*>(&part[(size_t)MN + i4]);
    float4 s2 = *reinterpret_cast<const float4*>(&part[(size_t)2*MN + i4]);
    float4 s3 = *reinterpret_cast<const float4*>(&part[(size_t)3*MN + i4]);
    float4 bb = *reinterpret_cast<const float4*>(&bias[i4 & Nmask]);
    float4 r;
    r.x = s0.x+s1.x+s2.x+s3.x+bb.x;
    r.y = s0.y+s1.y+s2.y+s3.y+bb.y;
    r.z = s0.z+s1.z+s2.z+s3.z+bb.z;
    r.w = s0.w+s1.w+s2.w+s3.w+bb.w;
    if (relu){ r.x=fmaxf(r.x,0.f); r.y=fmaxf(r.y,0.f); r.z=fmaxf(r.z,0.f); r.w=fmaxf(r.w,0.f); }
    *reinterpret_cast<float4*>(&out[i4]) = r;
  }
}

// ---------- 8. cls/box heads ----------
__global__ __launch_bounds__(256) void fc_heads(
    const float* __restrict__ x,
    const float* __restrict__ wcls, const float* __restrict__ bcls,
    const float* __restrict__ wbox, const float* __restrict__ bbox,
    float* __restrict__ cls, float* __restrict__ box){
  int row = blockIdx.x, tid = threadIdx.x;
  __shared__ float xs[1024];
  *reinterpret_cast<float4*>(&xs[tid*4]) =
      *reinterpret_cast<const float4*>(&x[(size_t)row*1024 + tid*4]);
  __syncthreads();
  int w = tid >> 6, lane = tid & 63;
  for (int o=w; o<10; o+=4){
    float p = 0.f;
    if (o < 2){
      for (int k=lane;k<1024;k+=64) p += xs[k]*wcls[(size_t)k*2 + o];
    } else {
      int q = o-2;
      for (int k=lane;k<1024;k+=64) p += xs[k]*wbox[(size_t)k*8 + q];
    }
    #pragma unroll
    for (int off=32; off>0; off>>=1) p += __shfl_down(p, off);
    if (lane==0){
      if (o<2) cls[(size_t)row*2 + o] = p + bcls[o];
      else     box[(size_t)row*8 + (o-2)] = p + bbox[o-2];
    }
  }
}

// ---------- 9. per-batch postprocess ----------
__global__ __launch_bounds__(1024) void postprocess_kernel(
    const float* __restrict__ cls, const float* __restrict__ boxd,
    const float* __restrict__ props, float* __restrict__ out){
  int b = blockIdx.x, tid = threadIdx.x;
  __shared__ float pb[512][4];
  __shared__ float sraw[512];
  __shared__ float s2a[512];
  __shared__ unsigned long long keys[512];
  __shared__ unsigned short order_[512];
  __shared__ unsigned char kval[512];
  __shared__ unsigned char korig[512];
  __shared__ unsigned long long pm[512][8];
  __shared__ volatile unsigned long long kw2[8];
  if (tid < 8) kw2[tid] = ~0ull;
  if (tid < 512){
    int r = b*512 + tid;
    float c0 = cls[(size_t)r*2+0], c1 = cls[(size_t)r*2+1];
    float mx = fmaxf(c0,c1);
    float e0 = expf(c0-mx), e1 = expf(c1-mx);
    float s = e1/(e0+e1);
    const float* pr = props + (size_t)r*4;
    float x1=pr[0], y1=pr[1], x2=pr[2], y2=pr[3];
    float w = x2-x1, h = y2-y1;
    float cx = x1 + 0.5f*w, cy = y1 + 0.5f*h;
    const float* dl = boxd + (size_t)r*8 + 4;
    float dx = dl[0]/10.f, dy = dl[1]/10.f;
    float dw = fminf(dl[2]/5.f, CLIPF), dh = fminf(dl[3]/5.f, CLIPF);
    float pcx = dx*w + cx, pcy = dy*h + cy;
    float pw = expf(dw)*w, ph = expf(dh)*h;
    float bx1 = fminf(fmaxf(pcx-0.5f*pw,0.f), IMGF);
    float by1 = fminf(fmaxf(pcy-0.5f*ph,0.f), IMGF);
    float bx2 = fminf(fmaxf(pcx+0.5f*pw,0.f), IMGF);
    float by2 = fminf(fmaxf(pcy+0.5f*ph,0.f), IMGF);
    pb[tid][0]=bx1; pb[tid][1]=by1; pb[tid][2]=bx2; pb[tid][3]=by2;
    bool valid = (s > 0.05f) && (bx2-bx1 >= 1e-2f) && (by2-by1 >= 1e-2f);
    sraw[tid]=s; kval[tid] = valid ? 1 : 0;
    float sm = valid ? s : -1e9f;
    keys[tid] = ((unsigned long long)fkey(sm)<<32) | (uint32_t)(~(uint32_t)tid);
  }
  __syncthreads();
  bitonic_desc(keys, 512, tid, 1024);
  if (tid < 512) order_[tid] = (unsigned short)(~(uint32_t)keys[tid]);
  __syncthreads();
  {
    int r = tid >> 1;
    int oi = order_[r];
    float ax1=pb[oi][0],ay1=pb[oi][1],ax2=pb[oi][2],ay2=pb[oi][3];
    float aa=(ax2-ax1)*(ay2-ay1);
    #pragma unroll
    for (int wo=0; wo<4; ++wo){
      int w = (tid&1)*4 + wo;
      unsigned long long m = 0ull;
      for (int jj=0;jj<64;jj++){
        int j = w*64 + jj;
        if (j > r){
          int oj = order_[j];
          float bx1=pb[oj][0],by1=pb[oj][1],bx2=pb[oj][2],by2=pb[oj][3];
          float ab=(bx2-bx1)*(by2-by1);
          float lx=fmaxf(ax1,bx1), ly=fmaxf(ay1,by1);
          float rx=fminf(ax2,bx2), ry=fminf(ay2,by2);
          float iw=fmaxf(rx-lx,0.f), ih=fmaxf(ry-ly,0.f);
          float inter=iw*ih;
          if (inter/(aa+ab-inter+1e-9f) > 0.5f) m |= (1ull<<jj);
        }
      }
      pm[r][w] = m;
    }
  }
  __syncthreads();
  if (tid < 8){
    for (int i=0;i<512;i++){
      unsigned long long kwv = kw2[i>>6];
      if ((kwv>>(i&63)) & 1ull) kw2[tid] &= ~pm[i][tid];
    }
  }
  __syncthreads();
  if (tid < 512){
    unsigned long long kwv = kw2[tid>>6];
    korig[order_[tid]] = (unsigned char)((kwv>>(tid&63)) & 1ull);
  }
  __syncthreads();
  if (tid < 512){
    float s2 = (korig[tid] && kval[tid]) ? sraw[tid] : 0.f;
    s2a[tid] = s2;
    keys[tid] = ((unsigned long long)fkey(s2)<<32) | (uint32_t)(~(uint32_t)tid);
  }
  __syncthreads();
  bitonic_desc(keys, 512, tid, 1024);
  if (tid < 100){
    uint32_t idx = ~(uint32_t)keys[tid];
    float ts = s2a[idx];
    float ok = (ts > 0.f) ? 1.f : 0.f;
    float* op = out + ((size_t)b*100 + tid)*6;
    op[0]=pb[idx][0]*ok; op[1]=pb[idx][1]*ok;
    op[2]=pb[idx][2]*ok; op[3]=pb[idx][3]*ok;
    op[4]=ts; op[5]=ok;
  }
}

// ---------- host launch ----------
extern "C" void kernel_launch(void* const* d_in, const int* in_sizes, int n_in,
                              void* d_out, int out_size, void* d_ws, size_t ws_size,
                              hipStream_t stream){
  (void)in_sizes; (void)n_in; (void)out_size; (void)ws_size;
  const float* feat[3] = {(const float*)d_in[0], (const float*)d_in[1], (const float*)d_in[2]};
  const float* rpn_conv_w = (const float*)d_in[3];
  const float* rpn_conv_b = (const float*)d_in[4];
  const float* rpn_cls_w  = (const float*)d_in[5];
  const float* rpn_cls_b  = (const float*)d_in[6];
  const float* rpn_box_w  = (const float*)d_in[7];
  const float* rpn_box_b  = (const float*)d_in[8];
  const float* fc1_w = (const float*)d_in[9];
  const float* fc1_b = (const float*)d_in[10];
  const float* fc2_w = (const float*)d_in[11];
  const float* fc2_b = (const float*)d_in[12];
  const float* cls_w = (const float*)d_in[13];
  const float* cls_b = (const float*)d_in[14];
  const float* box_w = (const float*)d_in[15];
  const float* box_b = (const float*)d_in[16];

  float* ws = (float*)d_ws;
  float* featT = ws;                        // 6,720,000 (live transpose..roi_align)
  float* fc1o  = ws;                        // 1,048,576 (after roi)
  float* fc2o  = ws + 1048576;              // 1,048,576
  float* clsb  = ws + 2097152;              //     2,048
  float* boxb  = ws + 2099200;              //     8,192
  float* parts = ws + 2107392;              // 4,194,304 -> ends 6,301,696
  float* props = ws + 6720000;              //     4,096
  float* roiX  = ws + 6724096;              // 12,845,056
  float* tP    = roiX;                      // 6,720,000 (conv output, position-major)
  float* objs       = roiX + 6720000;       //   393,750
  float* dels       = roiX + 7113750;       // 1,575,000
  float* lvl_boxes  = roiX + 8688750;       //    12,000
  float* lvl_scores = roiX + 8700750;       //     3,000
  float* nms_snb    = roiX + 8703750;       //    12,288
  int*   nms_order  = (int*)(roiX + 8716038);
  unsigned long long* nms_masks = (unsigned long long*)(roiX + 8719110);
  float* wrp2  = roiX + 8866568;            //    20,480
  float* wB    = roiX + 8887048;            //   589,824 -> ends 9,476,872
  // top-k scratch (lives before roi_align overwrites roiX)
  uint32_t* gh1 = (uint32_t*)(roiX + 9476872);        // 6*4096
  uint32_t* gh2 = (uint32_t*)(roiX + 9501448);        // 6*4096
  uint32_t* gh3 = (uint32_t*)(roiX + 9526024);        // 6*256
  int*      candCnt = (int*)(roiX + 9527560);         // 8
  unsigned long long* cand = (unsigned long long*)(roiX + 9527568); // 6*4096 u64

  const int HWs[3]   = {10000,2500,625};
  const int lvlOff[3]= {0,150000,187500};
  const int posOff[3]= {0,10000,12500};

  repack_heads_w<<<80, 256, 0, stream>>>(rpn_cls_w, rpn_box_w, wrp2);
  repack_wB<<<2304, 256, 0, stream>>>(rpn_conv_w, wB);
  tk_zero<<<199, 256, 0, stream>>>(gh1, 6*4096*2 + 6*256 + 8);   // gh1,gh2,gh3,candCnt contiguous

  for (int l=0;l<3;l++){
    dim3 gt((HWs[l]+31)/32, 8, 2);
    feat_transpose<<<gt, 256, 0, stream>>>(feat[l], featT, HWs[l], posOff[l]);
  }
  conv_mfma<<<832, 256, 0, stream>>>(featT, wB, rpn_conv_b, tP);
  for (int l=0;l<3;l++){
    dim3 gh((HWs[l]+63)/64, 2);
    rpn_heads_pm<<<gh, 256, 0, stream>>>(tP, wrp2, rpn_cls_b, rpn_box_b,
                                         objs, dels, HWs[l], posOff[l], lvlOff[l]);
  }
  // parallel exact top-500 per (batch,level)
  tk_hist1<<<dim3(8,6), 1024, 0, stream>>>(objs, gh1);
  tk_hist2<<<dim3(8,6), 1024, 0, stream>>>(objs, gh1, gh2);
  tk_hist3<<<dim3(8,6), 1024, 0, stream>>>(objs, gh1, gh2, gh3);
  tk_compact<<<dim3(8,6), 1024, 0, stream>>>(objs, gh1, gh2, gh3, candCnt, cand);
  tk_sortdecode<<<dim3(3,2), 1024, 0, stream>>>(objs, dels, candCnt, cand, lvl_boxes, lvl_scores);

  nms_sort<<<2, 1024, 0, stream>>>(lvl_boxes, lvl_scores, nms_snb, nms_order);
  nms_mask<<<dim3(24,2), 256, 0, stream>>>(nms_snb, nms_masks);
  nms_scan_final<<<2, 1024, 0, stream>>>(nms_masks, nms_order, lvl_boxes, lvl_scores, props);
  roi_align<<<1024, 256, 0, stream>>>(featT, props, roiX);
  gemm_mfma<<<dim3(16,8,4), 256, 0, stream>>>(roiX, fc1_w, parts, 1024, 1024, 12544, 3136);
  reduce_splitk<<<1024, 256, 0, stream>>>(parts, fc1_b, fc1o, 1024*1024, 1023, 1);
  gemm_mfma<<<dim3(16,8,4), 256, 0, stream>>>(fc1o, fc2_w, parts, 1024, 1024, 1024, 256);
  reduce_splitk<<<1024, 256, 0, stream>>>(parts, fc2_b, fc2o, 1024*1024, 1023, 1);
  fc_heads<<<1024, 256, 0, stream>>>(fc2o, cls_w, cls_b, box_w, box_b, clsb, boxb);
  postprocess_kernel<<<2, 1024, 0, stream>>>(clsb, boxb, props, (float*)d_out);
}

// Round 13
// 1425.511 us; speedup vs baseline: 1.9092x; 1.2845x over previous
//
#include <hip/hip_runtime.h>
#include <hip/hip_bf16.h>
#include <stdint.h>

#define IMGF 800.0f
#define CLIPF 4.135166556742356f

typedef __attribute__((ext_vector_type(8))) short bf16x8;
typedef __attribute__((ext_vector_type(4))) float f32x4;
typedef __attribute__((ext_vector_type(8))) unsigned short u16x8;
#define MFMA32 __builtin_amdgcn_mfma_f32_16x16x32_bf16

// ---------- helpers ----------
__device__ __forceinline__ uint32_t fkey(float x){
  uint32_t b = __float_as_uint(x);
  return (b & 0x80000000u) ? ~b : (b | 0x80000000u);
}

__device__ __forceinline__ float bf2f(unsigned short h){
  return __uint_as_float(((uint32_t)h)<<16);
}

__device__ __forceinline__ unsigned short f2bf(float x){
  __hip_bfloat16 hb = __float2bfloat16(x);
  return *reinterpret_cast<unsigned short*>(&hb);
}

// 3-way bf16 split of a single float
__device__ __forceinline__ void split3(float x,
    unsigned short&h, unsigned short&m, unsigned short&l){
  h = f2bf(x);
  float r = x - bf2f(h);
  m = f2bf(r);
  float s = r - bf2f(m);
  l = f2bf(s);
}

// 3-way bf16 split (RNE cascade) of 2 floats
__device__ __forceinline__ void split3x2(float x0, float x1,
    unsigned short&h0, unsigned short&h1, unsigned short&m0, unsigned short&m1,
    unsigned short&l0, unsigned short&l1){
  __hip_bfloat162 hb = __float22bfloat162_rn(make_float2(x0,x1));
  ushort2 hu = *reinterpret_cast<ushort2*>(&hb);
  float r0 = x0 - bf2f(hu.x), r1 = x1 - bf2f(hu.y);
  __hip_bfloat162 mb = __float22bfloat162_rn(make_float2(r0,r1));
  ushort2 mu = *reinterpret_cast<ushort2*>(&mb);
  float s0 = r0 - bf2f(mu.x), s1 = r1 - bf2f(mu.y);
  __hip_bfloat162 lb = __float22bfloat162_rn(make_float2(s0,s1));
  ushort2 lu = *reinterpret_cast<ushort2*>(&lb);
  h0=hu.x; h1=hu.y; m0=mu.x; m1=mu.y; l0=lu.x; l1=lu.y;
}

// descending bitonic sort of n (pow2) uint64 keys in LDS
__device__ void bitonic_desc(unsigned long long* k, int n, int tid, int nthr){
  for (int kk=2; kk<=n; kk<<=1){
    for (int j=kk>>1; j>0; j>>=1){
      __syncthreads();
      for (int i=tid; i<n; i+=nthr){
        int ixj = i ^ j;
        if (ixj > i){
          unsigned long long a = k[i], b = k[ixj];
          bool up = ((i & kk) == 0);
          if ((a < b) == up){ k[i]=b; k[ixj]=a; }
        }
      }
    }
  }
  __syncthreads();
}

// ---------- 0. prep: conv-weight split planes + head-weight repack + topk zero ----------
// grid 2583: [0,2304) wB split, [2304,2384) heads repack, [2384,2583) zero
__global__ __launch_bounds__(256) void prep_all(
    const float* __restrict__ w, const float* __restrict__ wc,
    const float* __restrict__ wb,
    unsigned short* __restrict__ wBh, unsigned short* __restrict__ wBm,
    unsigned short* __restrict__ wBl, float* __restrict__ wrp2,
    uint32_t* __restrict__ zbuf){
  int bid = blockIdx.x;
  if (bid < 2304){
    int idx = bid*256 + threadIdx.x;          // < 589824
    int oc = idx & 255; int rest = idx >> 8;
    int ic = rest & 255; int d = rest >> 8;
    float v = w[((size_t)oc*256 + ic)*9 + d];
    unsigned short h,m,l; split3(v,h,m,l);
    wBh[idx]=h; wBm[idx]=m; wBl[idx]=l;
  } else if (bid < 2384){
    int idx = (bid-2304)*256 + threadIdx.x;
    if (idx < 4*256*20){
      int j = idx % 20; int rest = idx/20;
      int cc = rest & 255; int wv = rest >> 8;
      int o = wv + 4*j;
      float v = 0.f;
      if (j < 19 && o < 75) v = (o<15) ? wc[o*256+cc] : wb[(o-15)*256+cc];
      wrp2[idx] = v;
    }
  } else {
    int i = (bid-2384)*256 + threadIdx.x;
    if (i < 50696) zbuf[i] = 0u;
  }
}

// ---------- 1. conv3x3 implicit GEMM (MFMA bf16x6), pre-split B planes ----------
__global__ __launch_bounds__(256) void conv_mfma(
    const float* __restrict__ featT,
    const unsigned short* __restrict__ wBh, const unsigned short* __restrict__ wBm,
    const unsigned short* __restrict__ wBl,
    const float* __restrict__ bias, float* __restrict__ tP){
  __shared__ unsigned short Ah[128*40], Amm[128*40], Al[128*40];
  __shared__ unsigned short Bh[64*40],  Bmm[64*40],  Bl[64*40];
  const int tid = threadIdx.x;
  const int bid = blockIdx.x;
  const int xcd = bid & 7, jb = bid >> 3;
  const int rt  = xcd*26 + (jb >> 2);
  const int bn  = (jb & 3) * 64;
  const int b = rt / 104;
  const int i = rt - b*104;
  int base, HW, W, posOff;
  if (i < 79)      { base = i*128;        HW = 10000; W = 100; posOff = 0; }
  else if (i < 99) { base = (i-79)*128;   HW = 2500;  W = 50;  posOff = 10000; }
  else             { base = (i-99)*128;   HW = 625;   W = 25;  posOff = 12500; }
  const int gRowBase = b*13125 + posOff;

  const int lane = tid & 63, wv = tid >> 6;
  const int wm = (wv>>1)*64, wn = (wv&1)*32;
  const int fr = lane & 15, fq = lane >> 4;

  const int arow = tid >> 1;
  const int ak   = (tid & 1) * 16;
  const int apos = base + arow;
  const bool av  = apos < HW;
  const int ay = apos / W, ax = apos - ay*W;
  const float* arowp = featT + (size_t)(gRowBase + apos)*256;
  const int bnl = tid & 63, bk0 = (tid >> 6) * 8;

  f32x4 acc[4][2];
  #pragma unroll
  for (int mi=0;mi<4;mi++)
    #pragma unroll
    for (int ni=0;ni<2;ni++) acc[mi][ni] = (f32x4){0.f,0.f,0.f,0.f};

  float va[16];
  u16x8 vbh, vbm, vbl;
  int dcur = -1, shift = 0; bool okf = false;

  auto loadA = [&](int step){
    const int kb = step*32;
    const int d  = kb >> 8;
    if (d != dcur){
      dcur = d;
      const int q3 = (d*11) >> 5;
      const int dy = q3 - 1, dx = d - 3*q3 - 1;
      shift = (dy*W + dx)*256;
      okf = av && (unsigned)(ay+dy) < (unsigned)W && (unsigned)(ax+dx) < (unsigned)W;
    }
    const int ic0 = (kb & 255) + ak;
    if (okf){
      #pragma unroll
      for (int c=0;c<4;c++){
        float4 f = *reinterpret_cast<const float4*>(arowp + shift + ic0 + c*4);
        va[c*4+0]=f.x; va[c*4+1]=f.y; va[c*4+2]=f.z; va[c*4+3]=f.w;
      }
    } else {
      #pragma unroll
      for (int c=0;c<16;c++) va[c]=0.f;
    }
  };
  auto loadB = [&](int step){
    const int kb = step*32;
    #pragma unroll
    for (int j=0;j<8;j++){
      size_t idx = (size_t)(kb + bk0 + j)*256 + bn + bnl;
      vbh[j] = wBh[idx]; vbm[j] = wBm[idx]; vbl[j] = wBl[idx];
    }
  };
  auto storeAB = [&](){
    u16x8 h[2], m[2], l[2];
    #pragma unroll
    for (int c=0;c<2;c++)
      #pragma unroll
      for (int p=0;p<4;p++){
        unsigned short h0,h1,m0,m1,l0,l1;
        split3x2(va[c*8+p*2], va[c*8+p*2+1], h0,h1,m0,m1,l0,l1);
        h[c][p*2]=h0; h[c][p*2+1]=h1;
        m[c][p*2]=m0; m[c][p*2+1]=m1;
        l[c][p*2]=l0; l[c][p*2+1]=l1;
      }
    const int ao = arow*40 + ak;
    *reinterpret_cast<u16x8*>(&Ah [ao])   = h[0];
    *reinterpret_cast<u16x8*>(&Ah [ao+8]) = h[1];
    *reinterpret_cast<u16x8*>(&Amm[ao])   = m[0];
    *reinterpret_cast<u16x8*>(&Amm[ao+8]) = m[1];
    *reinterpret_cast<u16x8*>(&Al [ao])   = l[0];
    *reinterpret_cast<u16x8*>(&Al [ao+8]) = l[1];
    const int bo = bnl*40 + bk0;
    *reinterpret_cast<u16x8*>(&Bh [bo]) = vbh;
    *reinterpret_cast<u16x8*>(&Bmm[bo]) = vbm;
    *reinterpret_cast<u16x8*>(&Bl [bo]) = vbl;
  };

  loadA(0); loadB(0);
  storeAB();
  __syncthreads();

  const int T = 72;
  for (int t=0; t<T; ++t){
    if (t+1 < T){ loadA(t+1); loadB(t+1); }
    bf16x8 aH[4], aM[4], aL[4];
    #pragma unroll
    for (int mi=0;mi<4;mi++){
      const int ro = (wm + mi*16 + fr)*40 + fq*8;
      aH[mi] = *reinterpret_cast<const bf16x8*>(&Ah [ro]);
      aM[mi] = *reinterpret_cast<const bf16x8*>(&Amm[ro]);
      aL[mi] = *reinterpret_cast<const bf16x8*>(&Al [ro]);
    }
    #pragma unroll
    for (int ni=0;ni<2;ni++){
      const int co = (wn + ni*16 + fr)*40 + fq*8;
      bf16x8 bH = *reinterpret_cast<const bf16x8*>(&Bh [co]);
      bf16x8 bM = *reinterpret_cast<const bf16x8*>(&Bmm[co]);
      bf16x8 bL = *reinterpret_cast<const bf16x8*>(&Bl [co]);
      #pragma unroll
      for (int mi=0;mi<4;mi++){
        f32x4 a = acc[mi][ni];
        a = MFMA32(aL[mi], bH, a, 0,0,0);
        a = MFMA32(aM[mi], bM, a, 0,0,0);
        a = MFMA32(aH[mi], bL, a, 0,0,0);
        a = MFMA32(aM[mi], bH, a, 0,0,0);
        a = MFMA32(aH[mi], bM, a, 0,0,0);
        a = MFMA32(aH[mi], bH, a, 0,0,0);
        acc[mi][ni] = a;
      }
    }
    if (t+1 < T){
      __syncthreads();
      storeAB();
      __syncthreads();
    }
  }

  #pragma unroll
  for (int mi=0;mi<4;mi++){
    #pragma unroll
    for (int ni=0;ni<2;ni++){
      const int col = bn + wn + ni*16 + fr;
      const float bz = bias[col];
      #pragma unroll
      for (int r=0;r<4;r++){
        const int pos = base + wm + mi*16 + fq*4 + r;
        if (pos < HW)
          tP[(size_t)(gRowBase+pos)*256 + col] = fmaxf(acc[mi][ni][r] + bz, 0.f);
      }
    }
  }
}

// ---------- 7. fc GEMM (MFMA bf16x6, split-K) ----------
__global__ __launch_bounds__(256) void gemm_mfma(
    const float* __restrict__ Am, const float* __restrict__ Bm,
    float* __restrict__ part, int M, int N, int K, int KC){
  __shared__ unsigned short Ah[128*40], Amm[128*40], Al[128*40];
  __shared__ unsigned short Bh[64*40],  Bmm[64*40],  Bl[64*40];
  const int tid = threadIdx.x;
  const int bn = blockIdx.x*64, bm = blockIdx.y*128, kz = blockIdx.z;
  const int k0 = kz*KC;
  const int T = KC/32;

  const int lane = tid & 63, wv = tid >> 6;
  const int wm = (wv>>1)*64, wn = (wv&1)*32;
  const int fr = lane & 15, fq = lane >> 4;

  const int arow = tid >> 1;
  const int ak   = (tid & 1) * 16;
  const int bnl = tid & 63, bk0 = (tid >> 6) * 8;

  f32x4 acc[4][2];
  #pragma unroll
  for (int mi=0;mi<4;mi++)
    #pragma unroll
    for (int ni=0;ni<2;ni++) acc[mi][ni] = (f32x4){0.f,0.f,0.f,0.f};

  float va[16], vb[8];

  auto loadA = [&](int kb){
    const float* p = &Am[(size_t)(bm+arow)*K + kb + ak];
    #pragma unroll
    for (int c=0;c<4;c++){
      float4 f = *reinterpret_cast<const float4*>(p + c*4);
      va[c*4+0]=f.x; va[c*4+1]=f.y; va[c*4+2]=f.z; va[c*4+3]=f.w;
    }
  };
  auto loadB = [&](int kb){
    #pragma unroll
    for (int j=0;j<8;j++) vb[j] = Bm[(size_t)(kb + bk0 + j)*N + bn + bnl];
  };
  auto storeAB = [&](){
    u16x8 h[2], m[2], l[2];
    #pragma unroll
    for (int c=0;c<2;c++)
      #pragma unroll
      for (int p=0;p<4;p++){
        unsigned short h0,h1,m0,m1,l0,l1;
        split3x2(va[c*8+p*2], va[c*8+p*2+1], h0,h1,m0,m1,l0,l1);
        h[c][p*2]=h0; h[c][p*2+1]=h1;
        m[c][p*2]=m0; m[c][p*2+1]=m1;
        l[c][p*2]=l0; l[c][p*2+1]=l1;
      }
    const int ao = arow*40 + ak;
    *reinterpret_cast<u16x8*>(&Ah [ao])   = h[0];
    *reinterpret_cast<u16x8*>(&Ah [ao+8]) = h[1];
    *reinterpret_cast<u16x8*>(&Amm[ao])   = m[0];
    *reinterpret_cast<u16x8*>(&Amm[ao+8]) = m[1];
    *reinterpret_cast<u16x8*>(&Al [ao])   = l[0];
    *reinterpret_cast<u16x8*>(&Al [ao+8]) = l[1];
    u16x8 hb, mb, lb;
    #pragma unroll
    for (int p=0;p<4;p++){
      unsigned short h0,h1,m0,m1,l0,l1;
      split3x2(vb[p*2], vb[p*2+1], h0,h1,m0,m1,l0,l1);
      hb[p*2]=h0; hb[p*2+1]=h1; mb[p*2]=m0; mb[p*2+1]=m1; lb[p*2]=l0; lb[p*2+1]=l1;
    }
    const int bo = bnl*40 + bk0;
    *reinterpret_cast<u16x8*>(&Bh [bo]) = hb;
    *reinterpret_cast<u16x8*>(&Bmm[bo]) = mb;
    *reinterpret_cast<u16x8*>(&Bl [bo]) = lb;
  };

  loadA(k0); loadB(k0);
  storeAB();
  __syncthreads();

  for (int t=0; t<T; ++t){
    if (t+1 < T){ loadA(k0 + (t+1)*32); loadB(k0 + (t+1)*32); }
    bf16x8 aH[4], aM[4], aL[4];
    #pragma unroll
    for (int mi=0;mi<4;mi++){
      const int ro = (wm + mi*16 + fr)*40 + fq*8;
      aH[mi] = *reinterpret_cast<const bf16x8*>(&Ah [ro]);
      aM[mi] = *reinterpret_cast<const bf16x8*>(&Amm[ro]);
      aL[mi] = *reinterpret_cast<const bf16x8*>(&Al [ro]);
    }
    #pragma unroll
    for (int ni=0;ni<2;ni++){
      const int co = (wn + ni*16 + fr)*40 + fq*8;
      bf16x8 bH = *reinterpret_cast<const bf16x8*>(&Bh [co]);
      bf16x8 bM = *reinterpret_cast<const bf16x8*>(&Bmm[co]);
      bf16x8 bL = *reinterpret_cast<const bf16x8*>(&Bl [co]);
      #pragma unroll
      for (int mi=0;mi<4;mi++){
        f32x4 a = acc[mi][ni];
        a = MFMA32(aL[mi], bH, a, 0,0,0);
        a = MFMA32(aM[mi], bM, a, 0,0,0);
        a = MFMA32(aH[mi], bL, a, 0,0,0);
        a = MFMA32(aM[mi], bH, a, 0,0,0);
        a = MFMA32(aH[mi], bM, a, 0,0,0);
        a = MFMA32(aH[mi], bH, a, 0,0,0);
        acc[mi][ni] = a;
      }
    }
    if (t+1 < T){
      __syncthreads();
      storeAB();
      __syncthreads();
    }
  }

  float* pz = part + (size_t)kz*M*N;
  #pragma unroll
  for (int mi=0;mi<4;mi++){
    #pragma unroll
    for (int ni=0;ni<2;ni++){
      const int col = bn + wn + ni*16 + fr;
      #pragma unroll
      for (int r=0;r<4;r++){
        const int row = bm + wm + mi*16 + fq*4 + r;
        pz[(size_t)row*N + col] = acc[mi][ni][r];
      }
    }
  }
}

// ---------- 2. RPN 1x1 heads (all levels, one launch) ----------
// grid (207, 2): x in [0,157) L0, [157,197) L1, [197,207) L2
__global__ __launch_bounds__(256) void rpn_heads_all(
    const float* __restrict__ tP, const float* __restrict__ wrp2,
    const float* __restrict__ bc, const float* __restrict__ bb,
    float* __restrict__ objs, float* __restrict__ dels){
  int bx = blockIdx.x;
  int HW, posOff, lvlOff, gx;
  if (bx < 157)      { gx = bx;     HW = 10000; posOff = 0;     lvlOff = 0; }
  else if (bx < 197) { gx = bx-157; HW = 2500;  posOff = 10000; lvlOff = 150000; }
  else               { gx = bx-197; HW = 625;   posOff = 12500; lvlOff = 187500; }
  int b = blockIdx.y;
  int p0 = gx*64;
  int lane = threadIdx.x & 63;
  int wv = __builtin_amdgcn_readfirstlane(threadIdx.x >> 6);
  __shared__ float sh[64][129];
  float acc[19];
  #pragma unroll
  for (int j=0;j<19;j++) acc[j]=0.f;
  const float* tb = tP + (size_t)(b*13125 + posOff)*256;
  for (int half=0; half<2; ++half){
    __syncthreads();
    for (int idx=threadIdx.x; idx<64*128; idx+=256){
      int px = idx>>7, c = idx&127;
      int p = p0+px;
      sh[px][c] = (p<HW) ? tb[(size_t)p*256 + half*128 + c] : 0.f;
    }
    __syncthreads();
    for (int c=0;c<128;c++){
      float v = sh[lane][c];
      int cc = half*128 + c;
      const float* wr = wrp2 + ((size_t)wv*256 + cc)*20;
      #pragma unroll
      for (int j=0;j<19;j++){
        int o = wv + 4*j;
        if (o < 75) acc[j] += v*wr[j];
      }
    }
  }
  int p = p0 + lane;
  if (p < HW){
    #pragma unroll
    for (int j=0;j<19;j++){
      int o = wv + 4*j;
      if (o < 75){
        if (o < 15){
          objs[(size_t)b*196875 + lvlOff + (size_t)p*15 + o] = acc[j] + bc[o];
        } else {
          int q = o-15;
          dels[((size_t)b*196875 + lvlOff + (size_t)p*15 + (q>>2))*4 + (q&3)] = acc[j] + bb[q];
        }
      }
    }
  }
}

// ---------- 3. feats NCHW -> position-major (all levels, one launch) ----------
// grid (412, 8, 2): x in [0,313) L0, [313,392) L1, [392,412) L2
__global__ __launch_bounds__(256) void feat_transpose_all(
    const float* __restrict__ f0, const float* __restrict__ f1,
    const float* __restrict__ f2, float* __restrict__ ft){
  __shared__ float tile[32][33];
  int bx = blockIdx.x;
  const float* f; int HW, posOff, gx;
  if (bx < 313)      { f = f0; gx = bx;     HW = 10000; posOff = 0; }
  else if (bx < 392) { f = f1; gx = bx-313; HW = 2500;  posOff = 10000; }
  else               { f = f2; gx = bx-392; HW = 625;   posOff = 12500; }
  int b = blockIdx.z;
  int p0 = gx*32, c0 = blockIdx.y*32;
  int tx = threadIdx.x & 31, ty = threadIdx.x >> 5;
  #pragma unroll
  for (int i=0;i<4;i++){
    int c = c0 + ty + i*8;
    int p = p0 + tx;
    tile[ty+i*8][tx] = (p<HW) ? f[((size_t)b*256 + c)*HW + p] : 0.f;
  }
  __syncthreads();
  #pragma unroll
  for (int i=0;i<4;i++){
    int p = p0 + ty + i*8;
    int c = c0 + tx;
    if (p < HW) ft[((size_t)b*13125 + posOff + p)*256 + c] = tile[tx][ty+i*8];
  }
}

// ================= parallel exact top-500 pipeline =================
__device__ __forceinline__ void tk_params(int pl, int& b, int& lvl, int& N, int& off){
  b = pl/3; lvl = pl - b*3;
  const int Ns[3]   = {150000,37500,9375};
  const int Offs[3] = {0,150000,187500};
  N = Ns[lvl]; off = Offs[lvl];
}

__device__ void suffix_select(uint32_t* s, int NB, int K, int tid,
                              int* outB, int* outK){
  for (int step=1; step<NB; step<<=1){
    uint32_t v[4]; int c=0;
    for (int i=tid;i<NB;i+=1024){ v[c++] = s[i] + ((i+step<NB)?s[i+step]:0u); }
    __syncthreads();
    c=0;
    for (int i=tid;i<NB;i+=1024) s[i]=v[c++];
    __syncthreads();
  }
  for (int i=tid;i<NB;i+=1024){
    int sufi = (int)s[i];
    int sufn = (i+1<NB)?(int)s[i+1]:0;
    if (sufi >= K && sufn < K){ *outB = i; *outK = K - sufn; }
  }
  __syncthreads();
}

__global__ __launch_bounds__(1024) void tk_hist1(
    const float* __restrict__ objs, uint32_t* __restrict__ gh1){
  __shared__ uint32_t h[4096];
  int pl = blockIdx.y, b, lvl, N, off;
  tk_params(pl,b,lvl,N,off);
  const float* sc = objs + (size_t)b*196875 + off;
  int tid = threadIdx.x;
  for (int i=tid;i<4096;i+=1024) h[i]=0u;
  __syncthreads();
  int cs = (N+7)>>3;
  int s0 = blockIdx.x*cs, s1 = s0+cs; if (s1>N) s1=N;
  for (int i=s0+tid;i<s1;i+=1024) atomicAdd(&h[fkey(sc[i])>>20],1u);
  __syncthreads();
  uint32_t* g = gh1 + pl*4096;
  for (int i=tid;i<4096;i+=1024) if(h[i]) atomicAdd(&g[i],h[i]);
}

__global__ __launch_bounds__(1024) void tk_hist2(
    const float* __restrict__ objs, const uint32_t* __restrict__ gh1,
    uint32_t* __restrict__ gh2){
  __shared__ uint32_t s[4096];
  __shared__ int sB, sK;
  int pl = blockIdx.y, b, lvl, N, off;
  tk_params(pl,b,lvl,N,off);
  const float* sc = objs + (size_t)b*196875 + off;
  int tid = threadIdx.x;
  for (int i=tid;i<4096;i+=1024) s[i]=gh1[pl*4096+i];
  __syncthreads();
  suffix_select(s,4096,500,tid,&sB,&sK);
  const uint32_t B1 = (uint32_t)sB;
  __syncthreads();
  for (int i=tid;i<4096;i+=1024) s[i]=0u;
  __syncthreads();
  int cs = (N+7)>>3;
  int s0 = blockIdx.x*cs, s1 = s0+cs; if (s1>N) s1=N;
  for (int i=s0+tid;i<s1;i+=1024){
    uint32_t u = fkey(sc[i]);
    if ((u>>20)==B1) atomicAdd(&s[(u>>8)&0xFFFu],1u);
  }
  __syncthreads();
  uint32_t* g = gh2 + pl*4096;
  for (int i=tid;i<4096;i+=1024) if(s[i]) atomicAdd(&g[i],s[i]);
}

__global__ __launch_bounds__(1024) void tk_hist3(
    const float* __restrict__ objs, const uint32_t* __restrict__ gh1,
    const uint32_t* __restrict__ gh2, uint32_t* __restrict__ gh3){
  __shared__ uint32_t s[4096];
  __shared__ int sB, sK;
  int pl = blockIdx.y, b, lvl, N, off;
  tk_params(pl,b,lvl,N,off);
  const float* sc = objs + (size_t)b*196875 + off;
  int tid = threadIdx.x;
  for (int i=tid;i<4096;i+=1024) s[i]=gh1[pl*4096+i];
  __syncthreads();
  suffix_select(s,4096,500,tid,&sB,&sK);
  const uint32_t B1 = (uint32_t)sB; const int k1 = sK;
  __syncthreads();
  for (int i=tid;i<4096;i+=1024) s[i]=gh2[pl*4096+i];
  __syncthreads();
  suffix_select(s,4096,k1,tid,&sB,&sK);
  const uint32_t B2 = (uint32_t)sB;
  const uint32_t pref24 = (B1<<12)|B2;
  __syncthreads();
  for (int i=tid;i<256;i+=1024) s[i]=0u;
  __syncthreads();
  int cs = (N+7)>>3;
  int s0 = blockIdx.x*cs, s1 = s0+cs; if (s1>N) s1=N;
  for (int i=s0+tid;i<s1;i+=1024){
    uint32_t u = fkey(sc[i]);
    if ((u>>8)==pref24) atomicAdd(&s[u & 0xFFu],1u);
  }
  __syncthreads();
  uint32_t* g = gh3 + pl*256;
  for (int i=tid;i<256;i+=1024) if(s[i]) atomicAdd(&g[i],s[i]);
}

__global__ __launch_bounds__(1024) void tk_compact(
    const float* __restrict__ objs, const uint32_t* __restrict__ gh1,
    const uint32_t* __restrict__ gh2, const uint32_t* __restrict__ gh3,
    int* __restrict__ candCnt, unsigned long long* __restrict__ cand){
  __shared__ uint32_t s[4096];
  __shared__ int sB, sK;
  int pl = blockIdx.y, b, lvl, N, off;
  tk_params(pl,b,lvl,N,off);
  const float* sc = objs + (size_t)b*196875 + off;
  int tid = threadIdx.x;
  for (int i=tid;i<4096;i+=1024) s[i]=gh1[pl*4096+i];
  __syncthreads();
  suffix_select(s,4096,500,tid,&sB,&sK);
  const uint32_t B1 = (uint32_t)sB; const int k1 = sK;
  __syncthreads();
  for (int i=tid;i<4096;i+=1024) s[i]=gh2[pl*4096+i];
  __syncthreads();
  suffix_select(s,4096,k1,tid,&sB,&sK);
  const uint32_t B2 = (uint32_t)sB; const int k2 = sK;
  __syncthreads();
  for (int i=tid;i<256;i+=1024) s[i]=gh3[pl*256+i];
  __syncthreads();
  suffix_select(s,256,k2,tid,&sB,&sK);
  const uint32_t B3 = (uint32_t)sB;
  const uint32_t T = (B1<<20)|(B2<<8)|B3;
  int cs = (N+7)>>3;
  int s0 = blockIdx.x*cs, s1 = s0+cs; if (s1>N) s1=N;
  unsigned long long* cp = cand + (size_t)pl*4096;
  for (int i=s0+tid;i<s1;i+=1024){
    uint32_t u = fkey(sc[i]);
    if (u >= T){
      int pos = atomicAdd(&candCnt[pl], 1);
      if (pos < 4096)
        cp[pos] = ((unsigned long long)u<<32) | (uint32_t)(~(uint32_t)i);
    }
  }
}

__global__ __launch_bounds__(1024) void tk_sortdecode(
    const float* __restrict__ objs, const float* __restrict__ dels,
    const int* __restrict__ candCnt, const unsigned long long* __restrict__ cand,
    float* __restrict__ lvl_boxes, float* __restrict__ lvl_scores){
  const int lvl = blockIdx.x, b = blockIdx.y;
  const int pl = b*3 + lvl;
  const int Offs[3] = {0,150000,187500};
  const int Wl[3]   = {100,50,25};
  const float strid[3] = {8.f,16.f,32.f};
  const float* sc = objs + (size_t)b*196875 + Offs[lvl];
  __shared__ unsigned long long keys[4096];
  int tid = threadIdx.x;
  int m = candCnt[pl]; if (m > 4096) m = 4096;
  int n = 512; while (n < m) n <<= 1;
  const unsigned long long* cp = cand + (size_t)pl*4096;
  for (int i=tid;i<n;i+=1024) keys[i] = (i<m) ? cp[i] : 0ull;
  __syncthreads();
  bitonic_desc(keys, n, tid, 1024);
  if (tid < 500){
    unsigned long long key = keys[tid];
    uint32_t idx = ~(uint32_t)(key & 0xFFFFFFFFull);
    float score = sc[idx];
    int p = idx/15, a = idx - p*15;
    int W = Wl[lvl];
    int hh = p / W, ww = p - hh*W;
    int r5 = a/5, s5 = a - r5*5;
    const float ratios[3] = {0.5f,1.0f,2.0f};
    const float scales[5] = {32.f,64.f,128.f,256.f,512.f};
    float hr = sqrtf(ratios[r5]); float wr = 1.0f/hr;
    float wsz = wr*scales[s5], hsz = hr*scales[s5];
    float sx = (float)ww*strid[lvl], sy = (float)hh*strid[lvl];
    float ax1 = sx - 0.5f*wsz, ay1 = sy - 0.5f*hsz;
    float ax2 = sx + 0.5f*wsz, ay2 = sy + 0.5f*hsz;
    const float* dl = dels + ((size_t)b*196875 + Offs[lvl] + idx)*4;
    float bw = ax2-ax1, bh = ay2-ay1;
    float cx = ax1 + 0.5f*bw, cy = ay1 + 0.5f*bh;
    float dx = dl[0], dy = dl[1];
    float dw = fminf(dl[2], CLIPF), dh = fminf(dl[3], CLIPF);
    float pcx = dx*bw + cx, pcy = dy*bh + cy;
    float pw = expf(dw)*bw, ph = expf(dh)*bh;
    float x1 = fminf(fmaxf(pcx - 0.5f*pw, 0.f), IMGF);
    float y1 = fminf(fmaxf(pcy - 0.5f*ph, 0.f), IMGF);
    float x2 = fminf(fmaxf(pcx + 0.5f*pw, 0.f), IMGF);
    float y2 = fminf(fmaxf(pcy + 0.5f*ph, 0.f), IMGF);
    int oidx = b*1500 + lvl*500 + tid;
    lvl_boxes[oidx*4+0]=x1; lvl_boxes[oidx*4+1]=y1;
    lvl_boxes[oidx*4+2]=x2; lvl_boxes[oidx*4+3]=y2;
    bool valid = (x2-x1 >= 1e-3f) && (y2-y1 >= 1e-3f);
    lvl_scores[oidx] = valid ? score : -1e9f;
  }
}

// ---------- 5a. NMS: sort by score ----------
__global__ __launch_bounds__(1024) void nms_sort(
    const float* __restrict__ lvl_boxes, const float* __restrict__ lvl_scores,
    float* __restrict__ snb, int* __restrict__ sorder){
  int b = blockIdx.x, tid = threadIdx.x;
  __shared__ unsigned long long keys[2048];
  const float* ls = lvl_scores + (size_t)b*1500;
  const float* lb = lvl_boxes + (size_t)b*1500*4;
  for (int i=tid;i<2048;i+=1024)
    keys[i] = (i<1500) ? (((unsigned long long)fkey(ls[i])<<32)|(uint32_t)(~(uint32_t)i)) : 0ull;
  __syncthreads();
  bitonic_desc(keys, 2048, tid, 1024);
  for (int r=tid;r<1536;r+=1024){
    if (r < 1500){
      int idx = (int)(~(uint32_t)keys[r]);
      sorder[(size_t)b*1536 + r] = idx;
      float offv = (float)(idx/500) * (IMGF + 16.0f);
      float* pp = snb + ((size_t)b*1536 + r)*4;
      pp[0]=lb[idx*4+0]+offv; pp[1]=lb[idx*4+1]+offv;
      pp[2]=lb[idx*4+2]+offv; pp[3]=lb[idx*4+3]+offv;
    } else {
      sorder[(size_t)b*1536 + r] = 0;
      float* pp = snb + ((size_t)b*1536 + r)*4;
      pp[0]=pp[1]=pp[2]=pp[3]=0.f;
    }
  }
}

// ---------- 5b. NMS: IoU suppression bitmask matrix ----------
__global__ __launch_bounds__(256) void nms_mask(
    const float* __restrict__ snb, unsigned long long* __restrict__ masks){
  int b = blockIdx.y;
  int i0 = blockIdx.x*64;
  __shared__ float sbx[1536][4];
  for (int t=threadIdx.x; t<1536*4; t+=256)
    sbx[t>>2][t&3] = snb[(size_t)b*1536*4 + t];
  __syncthreads();
  int il = threadIdx.x >> 2;
  int wq = threadIdx.x & 3;
  int i = i0 + il;
  float ax1=sbx[i][0], ay1=sbx[i][1], ax2=sbx[i][2], ay2=sbx[i][3];
  float aa=(ax2-ax1)*(ay2-ay1);
  #pragma unroll
  for (int wofs=0; wofs<6; ++wofs){
    int w = wq*6 + wofs;
    unsigned long long m = 0ull;
    if (i < 1500){
      for (int jj=0; jj<64; ++jj){
        int j = w*64 + jj;
        if (j > i && j < 1500){
          float bx1=sbx[j][0],by1=sbx[j][1],bx2=sbx[j][2],by2=sbx[j][3];
          float ab=(bx2-bx1)*(by2-by1);
          float lx=fmaxf(ax1,bx1), ly=fmaxf(ay1,by1);
          float rx=fminf(ax2,bx2), ry=fminf(ay2,by2);
          float iw=fmaxf(rx-lx,0.f), ih=fmaxf(ry-ly,0.f);
          float inter=iw*ih;
          if (inter/(aa+ab-inter+1e-9f) > 0.7f) m |= (1ull<<jj);
        }
      }
    }
    masks[((size_t)b*1536 + i)*24 + w] = m;
  }
}

// ---------- 5c. NMS: serial bitmask scan + final top-512 gather ----------
__global__ __launch_bounds__(1024) void nms_scan_final(
    const unsigned long long* __restrict__ masks, const int* __restrict__ sorder,
    const float* __restrict__ lvl_boxes, const float* __restrict__ lvl_scores,
    float* __restrict__ props){
  int b = blockIdx.x, tid = threadIdx.x;
  __shared__ unsigned long long cm[128][24];
  __shared__ volatile unsigned long long keepw[24];
  __shared__ unsigned char korig[1536];
  __shared__ unsigned long long keys[2048];
  if (tid < 24) keepw[tid] = (tid==23) ? ((1ull<<28)-1ull) : ~0ull;
  for (int c=0; c<12; ++c){
    __syncthreads();
    for (int t=tid; t<128*24; t+=1024)
      cm[t/24][t%24] = masks[((size_t)b*1536 + c*128)*24 + t];
    __syncthreads();
    if (tid < 24){
      int lim = (c==11) ? 84 : 128;
      for (int il=0; il<lim; ++il){
        int i = c*128 + il;
        unsigned long long kw = keepw[i>>6];
        if ((kw>>(i&63)) & 1ull) keepw[tid] &= ~cm[il][tid];
      }
    }
  }
  __syncthreads();
  for (int r=tid; r<1500; r+=1024){
    unsigned long long kw = keepw[r>>6];
    korig[sorder[(size_t)b*1536 + r]] = (unsigned char)((kw>>(r&63)) & 1ull);
  }
  __syncthreads();
  const float* ls = lvl_scores + (size_t)b*1500;
  const float* lb = lvl_boxes + (size_t)b*1500*4;
  for (int i=tid;i<2048;i+=1024){
    if (i<1500){
      float s = korig[i] ? ls[i] : -1e9f;
      keys[i] = ((unsigned long long)fkey(s)<<32)|(uint32_t)(~(uint32_t)i);
    } else keys[i]=0ull;
  }
  __syncthreads();
  bitonic_desc(keys, 2048, tid, 1024);
  for (int j=tid;j<512;j+=1024){
    int idx = (int)(~(uint32_t)keys[j]);
    float* pp = props + ((size_t)b*512 + j)*4;
    pp[0]=lb[idx*4+0]; pp[1]=lb[idx*4+1]; pp[2]=lb[idx*4+2]; pp[3]=lb[idx*4+3];
  }
}

// ---------- 6. ROI align ----------
__global__ __launch_bounds__(256) void roi_align(
    const float* __restrict__ featT, const float* __restrict__ props,
    float* __restrict__ roiX){
  int blk = blockIdx.x;
  int b = blk >> 9, n = blk & 511;
  const float* box = props + ((size_t)b*512 + n)*4;
  float x1=box[0], y1=box[1], x2=box[2], y2=box[3];
  float area = fmaxf(x2-x1,0.f)*fmaxf(y2-y1,0.f);
  float kf = floorf(4.0f + log2f(sqrtf(area)/224.0f + 1e-6f));
  kf = fminf(fmaxf(kf, 3.f), 5.f);
  int lvl = (int)kf - 3;
  const int Wl[3] = {100,50,25};
  const int posOff[3] = {0,10000,12500};
  const float strid[3] = {8.f,16.f,32.f};
  float scl = 1.0f/strid[lvl];
  float hw = (float)Wl[lvl];
  float rx1 = x1*scl, ry1 = y1*scl;
  float rw = fmaxf(x2*scl - rx1, 1.0f), rh = fmaxf(y2*scl - ry1, 1.0f);
  float bw = rw/7.0f, bh = rh/7.0f;
  __shared__ int sIdx[196][4];
  __shared__ float sW[196][4];
  int t = threadIdx.x;
  if (t < 196){
    int bin = t>>2, s = t&3;
    int py = bin/7, px = bin - py*7;
    int sy = s>>1, sx = s&1;
    float sgy = ((float)sy + 0.5f)*0.5f, sgx = ((float)sx + 0.5f)*0.5f;
    float Y = ry1 + ((float)py + sgy)*bh;
    float X = rx1 + ((float)px + sgx)*bw;
    Y = fminf(fmaxf(Y,0.f), hw-1.0f);
    X = fminf(fmaxf(X,0.f), hw-1.0f);
    float y0 = floorf(Y), x0 = floorf(X);
    float ly = Y-y0, lx = X-x0;
    int y0i=(int)y0, x0i=(int)x0;
    int hi = Wl[lvl]-1;
    int y1i = (y0i+1<hi)?(y0i+1):hi;
    int x1i = (x0i+1<hi)?(x0i+1):hi;
    int W = Wl[lvl];
    int base = b*13125 + posOff[lvl];
    sIdx[t][0] = (base + y0i*W + x0i)*256;
    sIdx[t][1] = (base + y0i*W + x1i)*256;
    sIdx[t][2] = (base + y1i*W + x0i)*256;
    sIdx[t][3] = (base + y1i*W + x1i)*256;
    sW[t][0]=(1.f-ly)*(1.f-lx); sW[t][1]=(1.f-ly)*lx;
    sW[t][2]=ly*(1.f-lx);       sW[t][3]=ly*lx;
  }
  __syncthreads();
  int c = t;
  float* orow = roiX + ((size_t)b*512 + n)*12544 + (size_t)c*49;
  for (int bin=0;bin<49;bin++){
    float acc = 0.f;
    #pragma unroll
    for (int s=0;s<4;s++){
      int tt = bin*4+s;
      acc += sW[tt][0]*featT[sIdx[tt][0]+c] + sW[tt][1]*featT[sIdx[tt][1]+c]
           + sW[tt][2]*featT[sIdx[tt][2]+c] + sW[tt][3]*featT[sIdx[tt][3]+c];
    }
    orow[bin] = acc*0.25f;
  }
}

// reduce SPLITK=4 partials + bias (+relu)
__global__ __launch_bounds__(256) void reduce_splitk(
    const float* __restrict__ part, const float* __restrict__ bias,
    float* __restrict__ out, int MN, int Nmask, int relu){
  int i4 = (blockIdx.x*256 + threadIdx.x)*4;
  if (i4 < MN){
    float4 s0 = *reinterpret_cast<const float4*>(&part[i4]);
    float4 s1 = *reinterpret_cast<const float4*>(&part[(size_t)MN + i4]);
    float4 s2 = *reinterpret_cast<const float4*>(&part[(size_t)2*MN + i4]);
    float4 s3 = *reinterpret_cast<const float4*>(&part[(size_t)3*MN + i4]);
    float4 bb = *reinterpret_cast<const float4*>(&bias[i4 & Nmask]);
    float4 r;
    r.x = s0.x+s1.x+s2.x+s3.x+bb.x;
    r.y = s0.y+s1.y+s2.y+s3.y+bb.y;
    r.z = s0.z+s1.z+s2.z+s3.z+bb.z;
    r.w = s0.w+s1.w+s2.w+s3.w+bb.w;
    if (relu){ r.x=fmaxf(r.x,0.f); r.y=fmaxf(r.y,0.f); r.z=fmaxf(r.z,0.f); r.w=fmaxf(r.w,0.f); }
    *reinterpret_cast<float4*>(&out[i4]) = r;
  }
}

// ---------- 8. cls/box heads ----------
__global__ __launch_bounds__(256) void fc_heads(
    const float* __restrict__ x,
    const float* __restrict__ wcls, const float* __restrict__ bcls,
    const float* __restrict__ wbox, const float* __restrict__ bbox,
    float* __restrict__ cls, float* __restrict__ box){
  int row = blockIdx.x, tid = threadIdx.x;
  __shared__ float xs[1024];
  *reinterpret_cast<float4*>(&xs[tid*4]) =
      *reinterpret_cast<const float4*>(&x[(size_t)row*1024 + tid*4]);
  __syncthreads();
  int w = tid >> 6, lane = tid & 63;
  for (int o=w; o<10; o+=4){
    float p = 0.f;
    if (o < 2){
      for (int k=lane;k<1024;k+=64) p += xs[k]*wcls[(size_t)k*2 + o];
    } else {
      int q = o-2;
      for (int k=lane;k<1024;k+=64) p += xs[k]*wbox[(size_t)k*8 + q];
    }
    #pragma unroll
    for (int off=32; off>0; off>>=1) p += __shfl_down(p, off);
    if (lane==0){
      if (o<2) cls[(size_t)row*2 + o] = p + bcls[o];
      else     box[(size_t)row*8 + (o-2)] = p + bbox[o-2];
    }
  }
}

// ---------- 9. per-batch postprocess ----------
__global__ __launch_bounds__(1024) void postprocess_kernel(
    const float* __restrict__ cls, const float* __restrict__ boxd,
    const float* __restrict__ props, float* __restrict__ out){
  int b = blockIdx.x, tid = threadIdx.x;
  __shared__ float pb[512][4];
  __shared__ float sraw[512];
  __shared__ float s2a[512];
  __shared__ unsigned long long keys[512];
  __shared__ unsigned short order_[512];
  __shared__ unsigned char kval[512];
  __shared__ unsigned char korig[512];
  __shared__ unsigned long long pm[512][8];
  __shared__ volatile unsigned long long kw2[8];
  if (tid < 8) kw2[tid] = ~0ull;
  if (tid < 512){
    int r = b*512 + tid;
    float c0 = cls[(size_t)r*2+0], c1 = cls[(size_t)r*2+1];
    float mx = fmaxf(c0,c1);
    float e0 = expf(c0-mx), e1 = expf(c1-mx);
    float s = e1/(e0+e1);
    const float* pr = props + (size_t)r*4;
    float x1=pr[0], y1=pr[1], x2=pr[2], y2=pr[3];
    float w = x2-x1, h = y2-y1;
    float cx = x1 + 0.5f*w, cy = y1 + 0.5f*h;
    const float* dl = boxd + (size_t)r*8 + 4;
    float dx = dl[0]/10.f, dy = dl[1]/10.f;
    float dw = fminf(dl[2]/5.f, CLIPF), dh = fminf(dl[3]/5.f, CLIPF);
    float pcx = dx*w + cx, pcy = dy*h + cy;
    float pw = expf(dw)*w, ph = expf(dh)*h;
    float bx1 = fminf(fmaxf(pcx-0.5f*pw,0.f), IMGF);
    float by1 = fminf(fmaxf(pcy-0.5f*ph,0.f), IMGF);
    float bx2 = fminf(fmaxf(pcx+0.5f*pw,0.f), IMGF);
    float by2 = fminf(fmaxf(pcy+0.5f*ph,0.f), IMGF);
    pb[tid][0]=bx1; pb[tid][1]=by1; pb[tid][2]=bx2; pb[tid][3]=by2;
    bool valid = (s > 0.05f) && (bx2-bx1 >= 1e-2f) && (by2-by1 >= 1e-2f);
    sraw[tid]=s; kval[tid] = valid ? 1 : 0;
    float sm = valid ? s : -1e9f;
    keys[tid] = ((unsigned long long)fkey(sm)<<32) | (uint32_t)(~(uint32_t)tid);
  }
  __syncthreads();
  bitonic_desc(keys, 512, tid, 1024);
  if (tid < 512) order_[tid] = (unsigned short)(~(uint32_t)keys[tid]);
  __syncthreads();
  {
    int r = tid >> 1;
    int oi = order_[r];
    float ax1=pb[oi][0],ay1=pb[oi][1],ax2=pb[oi][2],ay2=pb[oi][3];
    float aa=(ax2-ax1)*(ay2-ay1);
    #pragma unroll
    for (int wo=0; wo<4; ++wo){
      int w = (tid&1)*4 + wo;
      unsigned long long m = 0ull;
      for (int jj=0;jj<64;jj++){
        int j = w*64 + jj;
        if (j > r){
          int oj = order_[j];
          float bx1=pb[oj][0],by1=pb[oj][1],bx2=pb[oj][2],by2=pb[oj][3];
          float ab=(bx2-bx1)*(by2-by1);
          float lx=fmaxf(ax1,bx1), ly=fmaxf(ay1,by1);
          float rx=fminf(ax2,bx2), ry=fminf(ay2,by2);
          float iw=fmaxf(rx-lx,0.f), ih=fmaxf(ry-ly,0.f);
          float inter=iw*ih;
          if (inter/(aa+ab-inter+1e-9f) > 0.5f) m |= (1ull<<jj);
        }
      }
      pm[r][w] = m;
    }
  }
  __syncthreads();
  if (tid < 8){
    for (int i=0;i<512;i++){
      unsigned long long kwv = kw2[i>>6];
      if ((kwv>>(i&63)) & 1ull) kw2[tid] &= ~pm[i][tid];
    }
  }
  __syncthreads();
  if (tid < 512){
    unsigned long long kwv = kw2[tid>>6];
    korig[order_[tid]] = (unsigned char)((kwv>>(tid&63)) & 1ull);
  }
  __syncthreads();
  if (tid < 512){
    float s2 = (korig[tid] && kval[tid]) ? sraw[tid] : 0.f;
    s2a[tid] = s2;
    keys[tid] = ((unsigned long long)fkey(s2)<<32) | (uint32_t)(~(uint32_t)tid);
  }
  __syncthreads();
  bitonic_desc(keys, 512, tid, 1024);
  if (tid < 100){
    uint32_t idx = ~(uint32_t)keys[tid];
    float ts = s2a[idx];
    float ok = (ts > 0.f) ? 1.f : 0.f;
    float* op = out + ((size_t)b*100 + tid)*6;
    op[0]=pb[idx][0]*ok; op[1]=pb[idx][1]*ok;
    op[2]=pb[idx][2]*ok; op[3]=pb[idx][3]*ok;
    op[4]=ts; op[5]=ok;
  }
}

// ---------- host launch ----------
extern "C" void kernel_launch(void* const* d_in, const int* in_sizes, int n_in,
                              void* d_out, int out_size, void* d_ws, size_t ws_size,
                              hipStream_t stream){
  (void)in_sizes; (void)n_in; (void)out_size; (void)ws_size;
  const float* feat0 = (const float*)d_in[0];
  const float* feat1 = (const float*)d_in[1];
  const float* feat2 = (const float*)d_in[2];
  const float* rpn_conv_w = (const float*)d_in[3];
  const float* rpn_conv_b = (const float*)d_in[4];
  const float* rpn_cls_w  = (const float*)d_in[5];
  const float* rpn_cls_b  = (const float*)d_in[6];
  const float* rpn_box_w  = (const float*)d_in[7];
  const float* rpn_box_b  = (const float*)d_in[8];
  const float* fc1_w = (const float*)d_in[9];
  const float* fc1_b = (const float*)d_in[10];
  const float* fc2_w = (const float*)d_in[11];
  const float* fc2_b = (const float*)d_in[12];
  const float* cls_w = (const float*)d_in[13];
  const float* cls_b = (const float*)d_in[14];
  const float* box_w = (const float*)d_in[15];
  const float* box_b = (const float*)d_in[16];

  float* ws = (float*)d_ws;
  float* featT = ws;                        // 6,720,000 (live transpose..roi_align)
  float* fc1o  = ws;                        // 1,048,576 (after roi)
  float* fc2o  = ws + 1048576;              // 1,048,576
  float* clsb  = ws + 2097152;              //     2,048
  float* boxb  = ws + 2099200;              //     8,192
  float* parts = ws + 2107392;              // 4,194,304 -> ends 6,301,696
  float* props = ws + 6720000;              //     4,096
  float* roiX  = ws + 6724096;              // 12,845,056
  float* tP    = roiX;                      // 6,720,000 (conv output)
  float* objs       = roiX + 6720000;       //   393,750
  float* dels       = roiX + 7113750;       // 1,575,000
  float* lvl_boxes  = roiX + 8688750;       //    12,000
  float* lvl_scores = roiX + 8700750;       //     3,000
  float* nms_snb    = roiX + 8703750;       //    12,288
  int*   nms_order  = (int*)(roiX + 8716038);
  unsigned long long* nms_masks = (unsigned long long*)(roiX + 8719110); // ends 8,866,566
  float* wrp2  = roiX + 8866568;            //    20,480 -> 8,887,048
  unsigned short* wBh = (unsigned short*)(roiX + 8887048);  // 589,824 shorts = 294,912 f
  unsigned short* wBm = (unsigned short*)(roiX + 9181960);
  unsigned short* wBl = (unsigned short*)(roiX + 9476872);  // -> 9,771,784
  uint32_t* gh1 = (uint32_t*)(roiX + 9771784);        // 24,576
  uint32_t* gh2 = (uint32_t*)(roiX + 9796360);        // 24,576
  uint32_t* gh3 = (uint32_t*)(roiX + 9820936);        //  1,536
  int*      candCnt = (int*)(roiX + 9822472);         //      8
  unsigned long long* cand = (unsigned long long*)(roiX + 9822480); // 49,152 f -> 9,871,632

  prep_all<<<2583, 256, 0, stream>>>(rpn_conv_w, rpn_cls_w, rpn_box_w,
                                     wBh, wBm, wBl, wrp2, gh1);
  feat_transpose_all<<<dim3(412,8,2), 256, 0, stream>>>(feat0, feat1, feat2, featT);
  conv_mfma<<<832, 256, 0, stream>>>(featT, wBh, wBm, wBl, rpn_conv_b, tP);
  rpn_heads_all<<<dim3(207,2), 256, 0, stream>>>(tP, wrp2, rpn_cls_b, rpn_box_b, objs, dels);
  tk_hist1<<<dim3(8,6), 1024, 0, stream>>>(objs, gh1);
  tk_hist2<<<dim3(8,6), 1024, 0, stream>>>(objs, gh1, gh2);
  tk_hist3<<<dim3(8,6), 1024, 0, stream>>>(objs, gh1, gh2, gh3);
  tk_compact<<<dim3(8,6), 1024, 0, stream>>>(objs, gh1, gh2, gh3, candCnt, cand);
  tk_sortdecode<<<dim3(3,2), 1024, 0, stream>>>(objs, dels, candCnt, cand, lvl_boxes, lvl_scores);
  nms_sort<<<2, 1024, 0, stream>>>(lvl_boxes, lvl_scores, nms_snb, nms_order);
  nms_mask<<<dim3(24,2), 256, 0, stream>>>(nms_snb, nms_masks);
  nms_scan_final<<<2, 1024, 0, stream>>>(nms_masks, nms_order, lvl_boxes, lvl_scores, props);
  roi_align<<<1024, 256, 0, stream>>>(featT, props, roiX);
  gemm_mfma<<<dim3(16,8,4), 256, 0, stream>>>(roiX, fc1_w, parts, 1024, 1024, 12544, 3136);
  reduce_splitk<<<1024, 256, 0, stream>>>(parts, fc1_b, fc1o, 1024*1024, 1023, 1);
  gemm_mfma<<<dim3(16,8,4), 256, 0, stream>>>(fc1o, fc2_w, parts, 1024, 1024, 1024, 256);
  reduce_splitk<<<1024, 256, 0, stream>>>(parts, fc2_b, fc2o, 1024*1024, 1023, 1);
  fc_heads<<<1024, 256, 0, stream>>>(fc2o, cls_w, cls_b, box_w, box_b, clsb, boxb);
  postprocess_kernel<<<2, 1024, 0, stream>>>(clsb, boxb, props, (float*)d_out);
}